// Round 8
// baseline (236.361 us; speedup 1.0000x reference)
//
#include <hip/hip_runtime.h>

#define NMET 200000
#define NRXN 400000
#define ESUB 800000
#define EALL 1600000

// met-bucket sort (consume + contrib): bucket = met >> 9, 512 mets/bucket
#define NBUCK_M 391                  // ceil(200000/512)
#define NBM 196                      // blocks for met counting/scatter
#define EBA 8192                     // met_all edges per block (196*8192 >= EALL)
#define EBS 4096                     // met_sub edges per block

// rxn-bucket sort (CSR replacement): bucket = rxn >> 9, 512 rxns/bucket
#define NBUCK_R 782                  // ceil(400000/512)
#define NBR 1024                     // blocks for rxn counting/scatter
#define EBR 782                      // edges per block (1024*782 >= ESUB)
#define MET_MASK 0x3FFFF             // 18 bits (NMET < 262144)

// c_target = 1 + 0.5*sin(2*pi*100/1000) = 1.2938926261462366
#define C_TARGET 1.29389262614623664f
#define DT_C 0.01f
#define HOMEO_C 0.1f
#define LOG2_10 3.32192809488736235f

__device__ __forceinline__ float fast_tanh(float x) {
    float e = __expf(2.0f * x);
    return 1.0f - 2.0f * __builtin_amdgcn_rcpf(e + 1.0f);
}

// ---- 1a. met-bucket counts for contrib (A) and consume (S) -----------------
__global__ __launch_bounds__(256) void k_count_met(
    const int* __restrict__ met_all, const int* __restrict__ met_sub,
    int* __restrict__ blockHistA, int* __restrict__ blockHistS)
{
    __shared__ int hA[NBUCK_M];
    __shared__ int hS[NBUCK_M];
    int t = threadIdx.x;
    for (int b = t; b < NBUCK_M; b += 256) { hA[b] = 0; hS[b] = 0; }
    __syncthreads();
    int baseA = blockIdx.x * EBA;
    for (int i = t; i < EBA; i += 256) {
        int e = baseA + i;
        if (e < EALL) atomicAdd(&hA[met_all[e] >> 9], 1);
    }
    int baseS = blockIdx.x * EBS;
    for (int i = t; i < EBS; i += 256) {
        int e = baseS + i;
        if (e < ESUB) atomicAdd(&hS[met_sub[e] >> 9], 1);
    }
    __syncthreads();
    for (int b = t; b < NBUCK_M; b += 256) {
        blockHistA[(size_t)b * NBM + blockIdx.x] = hA[b];
        blockHistS[(size_t)b * NBM + blockIdx.x] = hS[b];
    }
}

// ---- 1b. rxn-bucket counts --------------------------------------------------
__global__ __launch_bounds__(256) void k_count_rxn(
    const int* __restrict__ rxn_sub, int* __restrict__ blockHistR)
{
    __shared__ int hR[NBUCK_R];
    int t = threadIdx.x;
    for (int b = t; b < NBUCK_R; b += 256) hR[b] = 0;
    __syncthreads();
    int base = blockIdx.x * EBR;
    for (int i = t; i < EBR; i += 256) {
        int e = base + i;
        if (e < ESUB) atomicAdd(&hR[rxn_sub[e] >> 9], 1);
    }
    __syncthreads();
    for (int b = t; b < NBUCK_R; b += 256)
        blockHistR[(size_t)b * NBR + blockIdx.x] = hR[b];
}

// ---- 2. generic per-bucket scan over nb block counts (in place) ------------
__global__ __launch_bounds__(256) void k_bscan_g(
    int* __restrict__ hist, int* __restrict__ total, int nb)
{
    __shared__ int lds[256];
    __shared__ int carry_s;
    int t = threadIdx.x;
    size_t base = (size_t)blockIdx.x * nb;
    if (t == 0) carry_s = 0;
    __syncthreads();
    for (int off0 = 0; off0 < nb; off0 += 256) {
        int i = off0 + t;
        int val = (i < nb) ? hist[base + i] : 0;
        lds[t] = val;
        __syncthreads();
        for (int off = 1; off < 256; off <<= 1) {
            int add = (t >= off) ? lds[t - off] : 0;
            __syncthreads();
            lds[t] += add;
            __syncthreads();
        }
        int incl = lds[t];
        int carry = carry_s;
        if (i < nb) hist[base + i] = carry + incl - val;
        __syncthreads();
        if (t == 255) carry_s = carry + incl;
        __syncthreads();
    }
    if (t == 0) total[blockIdx.x] = carry_s;
}

// ---- 3. generic one-block scan of bucket totals -> bucketStart -------------
__global__ __launch_bounds__(1024) void k_bstart_g(
    const int* __restrict__ total, int* __restrict__ start, int nbuck)
{
    __shared__ int lds[1024];
    int t = threadIdx.x;
    int val = (t < nbuck) ? total[t] : 0;
    lds[t] = val;
    __syncthreads();
    for (int off = 1; off < 1024; off <<= 1) {
        int add = (t >= off) ? lds[t - off] : 0;
        __syncthreads();
        lds[t] += add;
        __syncthreads();
    }
    if (t < nbuck) start[t] = lds[t] - val;
    if (t == 1023) start[nbuck] = lds[1023];
}

// ---- 4. scatter rxn records {met | rloc<<18, sto} into rxn buckets ---------
__global__ __launch_bounds__(256) void k_rxn_scatter(
    const int* __restrict__ rxn_sub, const int* __restrict__ met_sub,
    const float* __restrict__ sto_sub,
    const int* __restrict__ blockHistR, const int* __restrict__ bucketStartR,
    uint2* __restrict__ recsR)
{
    __shared__ int bbase[NBUCK_R];
    __shared__ int h[NBUCK_R];
    int t = threadIdx.x;
    for (int b = t; b < NBUCK_R; b += 256) {
        h[b] = 0;
        bbase[b] = bucketStartR[b] + blockHistR[(size_t)b * NBR + blockIdx.x];
    }
    __syncthreads();
    int base = blockIdx.x * EBR;
    for (int i = t; i < EBR; i += 256) {
        int e = base + i;
        if (e < ESUB) {
            int r = rxn_sub[e];
            int b = r >> 9;
            int rloc = r & 511;
            int slot = bbase[b] + atomicAdd(&h[b], 1);
            uint2 rec;
            rec.x = (unsigned)(met_sub[e] | (rloc << 18));
            rec.y = __float_as_uint(sto_sub[e]);
            recsR[slot] = rec;
        }
    }
}

// ---- 5. per-rxn-bucket: edge MLP -> LDS segment sums -> rate MLP -> v ------
__global__ __launch_bounds__(256) void k_bucket_rxn(
    const uint2* __restrict__ recsR, const int* __restrict__ bucketStartR,
    const float* __restrict__ x,
    const float* __restrict__ sub_w1, const float* __restrict__ sub_b1,
    const float* __restrict__ sub_w2, const float* __restrict__ sub_b2,
    const float* __restrict__ rate_w1, const float* __restrict__ rate_b1,
    const float* __restrict__ rate_w2, const float* __restrict__ rate_b2,
    const float* __restrict__ log_k, float* __restrict__ v)
{
    __shared__ float sW1[128];
    __shared__ float sB1[64];
    __shared__ __align__(16) float sW2[512];
    __shared__ __align__(16) float sR1[512];
    __shared__ float sRB1[64];
    __shared__ float sR2[64];
    __shared__ float sB2[8];
    __shared__ float sRB2;
    __shared__ float h[512][9];     // +1 pad: spreads rloc*9 across all banks
    __shared__ float ext[512];
    __shared__ int   cnt[512];

    int t = threadIdx.x;
    for (int i = t; i < 128; i += 256) sW1[i] = sub_w1[i];
    for (int i = t; i < 64;  i += 256) {
        sB1[i] = sub_b1[i]; sRB1[i] = rate_b1[i]; sR2[i] = rate_w2[i];
    }
    for (int i = t; i < 512; i += 256) { sW2[i] = sub_w2[i]; sR1[i] = rate_w1[i]; }
    if (t < 8) sB2[t] = sub_b2[t];
    if (t == 8) sRB2 = rate_b2[0];
    for (int i = t; i < 512; i += 256) {
        ext[i] = 0.f; cnt[i] = 0;
        #pragma unroll
        for (int j = 0; j < 8; ++j) h[i][j] = 0.f;
    }
    __syncthreads();

    int b = blockIdx.x;
    int s = bucketStartR[b], epos = bucketStartR[b + 1];
    for (int i = s + t; i < epos; i += 256) {
        uint2 rec = recsR[i];
        int m    = rec.x & MET_MASK;
        int rloc = rec.x >> 18;
        float st = __uint_as_float(rec.y);
        float c  = x[(size_t)m * 8 + 3];
        float ex = x[(size_t)m * 8 + 4];
        float m0 = 0.f, m1 = 0.f, m2 = 0.f, m3 = 0.f;
        float m4 = 0.f, m5 = 0.f, m6 = 0.f, m7 = 0.f;
        #pragma unroll 8
        for (int j = 0; j < 64; ++j) {
            float z = fmaf(c, sW1[j], fmaf(st, sW1[64 + j], sB1[j]));
            float th = fast_tanh(z);
            float4 wa = *(const float4*)&sW2[j * 8];
            float4 wb = *(const float4*)&sW2[j * 8 + 4];
            m0 = fmaf(th, wa.x, m0); m1 = fmaf(th, wa.y, m1);
            m2 = fmaf(th, wa.z, m2); m3 = fmaf(th, wa.w, m3);
            m4 = fmaf(th, wb.x, m4); m5 = fmaf(th, wb.y, m5);
            m6 = fmaf(th, wb.z, m6); m7 = fmaf(th, wb.w, m7);
        }
        atomicAdd(&h[rloc][0], m0); atomicAdd(&h[rloc][1], m1);
        atomicAdd(&h[rloc][2], m2); atomicAdd(&h[rloc][3], m3);
        atomicAdd(&h[rloc][4], m4); atomicAdd(&h[rloc][5], m5);
        atomicAdd(&h[rloc][6], m6); atomicAdd(&h[rloc][7], m7);
        atomicAdd(&ext[rloc], ex);
        atomicAdd(&cnt[rloc], 1);
    }
    __syncthreads();

    int gbase = b << 9;
    for (int rr = t; rr < 512; rr += 256) {
        int gr = gbase + rr;
        if (gr >= NRXN) continue;
        float fn = (float)cnt[rr];
        float h0 = h[rr][0] + fn * sB2[0];
        float h1 = h[rr][1] + fn * sB2[1];
        float h2 = h[rr][2] + fn * sB2[2];
        float h3 = h[rr][3] + fn * sB2[3];
        float h4 = h[rr][4] + fn * sB2[4];
        float h5 = h[rr][5] + fn * sB2[5];
        float h6 = h[rr][6] + fn * sB2[6];
        float h7 = h[rr][7] + fn * sB2[7];
        float acc = sRB2;
        #pragma unroll 4
        for (int j = 0; j < 64; ++j) {
            float z = sRB1[j];
            z = fmaf(h0, sR1[j],       z);
            z = fmaf(h1, sR1[64 + j],  z);
            z = fmaf(h2, sR1[128 + j], z);
            z = fmaf(h3, sR1[192 + j], z);
            z = fmaf(h4, sR1[256 + j], z);
            z = fmaf(h5, sR1[320 + j], z);
            z = fmaf(h6, sR1[384 + j], z);
            z = fmaf(h7, sR1[448 + j], z);
            acc = fmaf(fast_tanh(z), sR2[j], acc);
        }
        float nmax = fmaxf(fn, 1.0f);
        float ext_mean = 2.0f * ext[rr] * __builtin_amdgcn_rcpf(nmax);
        float kk = exp2f(log_k[gr] * LOG2_10);
        v[gr] = kk * ext_mean * acc;
    }
}

// ---- 6. consume bucket-scatter (edge order, pre-limit v) -------------------
__global__ __launch_bounds__(256) void k_cons_scatter(
    const int* __restrict__ met_sub, const int* __restrict__ rxn_sub,
    const float* __restrict__ sto_sub, const float* __restrict__ v,
    const int* __restrict__ blockHistS, const int* __restrict__ bucketStartS,
    uint2* __restrict__ recsS)
{
    __shared__ int h[NBUCK_M];
    __shared__ int bbase[NBUCK_M];
    int t = threadIdx.x;
    for (int b = t; b < NBUCK_M; b += 256) {
        h[b] = 0;
        bbase[b] = bucketStartS[b] + blockHistS[(size_t)b * NBM + blockIdx.x];
    }
    __syncthreads();
    int base = blockIdx.x * EBS;
    for (int i = t; i < EBS; i += 256) {
        int e = base + i;
        if (e < ESUB) {
            int m = met_sub[e];
            int b = m >> 9;
            float val = sto_sub[e] * v[rxn_sub[e]] * DT_C;
            int r = atomicAdd(&h[b], 1);
            uint2 rec;
            rec.x = (unsigned)m;
            rec.y = __float_as_uint(val);
            recsS[bbase[b] + r] = rec;
        }
    }
}

// ---- 7. per-bucket accumulate total -> met_scale ---------------------------
__global__ __launch_bounds__(256) void k_baccum_tot(
    const uint2* __restrict__ recsS, const int* __restrict__ bucketStartS,
    const float* __restrict__ x, float* __restrict__ met_scale)
{
    __shared__ float acc[512];
    int b = blockIdx.x;
    int t = threadIdx.x;
    for (int j = t; j < 512; j += 256) acc[j] = 0.f;
    __syncthreads();
    int s = bucketStartS[b], epos = bucketStartS[b + 1];
    for (int i = s + t; i < epos; i += 256) {
        uint2 rec = recsS[i];
        atomicAdd(&acc[rec.x & 511], __uint_as_float(rec.y));
    }
    __syncthreads();
    int mbase = b << 9;
    for (int j = t; j < 512; j += 256) {
        int m = mbase + j;
        if (m < NMET) {
            float tot = acc[j];
            float ms = 1.0f;
            if (tot > 1e-12f) ms = fminf(x[(size_t)m * 8 + 3] / tot, 1.0f);
            met_scale[m] = ms;
        }
    }
}

// ---- 8. per-rxn-bucket min over records + v scale --------------------------
__global__ __launch_bounds__(256) void k_rscale_bucket(
    const uint2* __restrict__ recsR, const int* __restrict__ bucketStartR,
    const float* __restrict__ met_scale, float* __restrict__ v)
{
    __shared__ unsigned ms[512];
    int t = threadIdx.x;
    for (int i = t; i < 512; i += 256) ms[i] = 0x3f800000u;   // 1.0f
    __syncthreads();
    int b = blockIdx.x;
    int s = bucketStartR[b], epos = bucketStartR[b + 1];
    for (int i = s + t; i < epos; i += 256) {
        uint2 rec = recsR[i];
        int m    = rec.x & MET_MASK;
        int rloc = rec.x >> 18;
        atomicMin(&ms[rloc], __float_as_uint(met_scale[m]));  // all >= 0
    }
    __syncthreads();
    int gbase = b << 9;
    for (int rr = t; rr < 512; rr += 256) {
        int gr = gbase + rr;
        if (gr < NRXN) v[gr] *= __uint_as_float(ms[rr]);
    }
}

// ---- 9. contrib bucket-scatter (edge order, post-limit v) ------------------
__global__ __launch_bounds__(256) void k_bscatter(
    const int* __restrict__ met_all, const int* __restrict__ rxn_all,
    const float* __restrict__ sto_all, const float* __restrict__ v,
    const int* __restrict__ blockHistA, const int* __restrict__ bucketStartA,
    uint2* __restrict__ recsA)
{
    __shared__ int h[NBUCK_M];
    __shared__ int bbase[NBUCK_M];
    int t = threadIdx.x;
    for (int b = t; b < NBUCK_M; b += 256) {
        h[b] = 0;
        bbase[b] = bucketStartA[b] + blockHistA[(size_t)b * NBM + blockIdx.x];
    }
    __syncthreads();
    int base = blockIdx.x * EBA;
    for (int i = t; i < EBA; i += 256) {
        int e = base + i;
        if (e < EALL) {
            int m = met_all[e];
            int b = m >> 9;
            float val = sto_all[e] * v[rxn_all[e]];
            int r = atomicAdd(&h[b], 1);
            uint2 rec;
            rec.x = (unsigned)m;
            rec.y = __float_as_uint(val);
            recsA[bbase[b] + r] = rec;
        }
    }
}

// ---- 10. per-bucket accumulate + homeostasis epilogue ----------------------
__global__ __launch_bounds__(256) void k_baccum(
    const uint2* __restrict__ recsA, const int* __restrict__ bucketStartA,
    const float* __restrict__ x, float* __restrict__ out)
{
    __shared__ float acc[512];
    int b = blockIdx.x;
    int t = threadIdx.x;
    for (int j = t; j < 512; j += 256) acc[j] = 0.f;
    __syncthreads();
    int s = bucketStartA[b], epos = bucketStartA[b + 1];
    for (int i = s + t; i < epos; i += 256) {
        uint2 rec = recsA[i];
        atomicAdd(&acc[rec.x & 511], __uint_as_float(rec.y));
    }
    __syncthreads();
    int mbase = b << 9;
    for (int j = t; j < 512; j += 256) {
        int m = mbase + j;
        if (m < NMET) {
            float c = x[(size_t)m * 8 + 3];
            out[m] = acc[j] - HOMEO_C * (c - C_TARGET);
        }
    }
}

extern "C" void kernel_launch(void* const* d_in, const int* in_sizes, int n_in,
                              void* d_out, int out_size, void* d_ws, size_t ws_size,
                              hipStream_t stream) {
    const float* x       = (const float*)d_in[0];
    const int*   met_sub = (const int*)  d_in[1];
    const int*   rxn_sub = (const int*)  d_in[2];
    const float* sto_sub = (const float*)d_in[3];
    const int*   met_all = (const int*)  d_in[4];
    const int*   rxn_all = (const int*)  d_in[5];
    const float* sto_all = (const float*)d_in[6];
    const float* sub_w1  = (const float*)d_in[7];
    const float* sub_b1  = (const float*)d_in[8];
    const float* sub_w2  = (const float*)d_in[9];
    const float* sub_b2  = (const float*)d_in[10];
    const float* rate_w1 = (const float*)d_in[11];
    const float* rate_b1 = (const float*)d_in[12];
    const float* rate_w2 = (const float*)d_in[13];
    const float* rate_b2 = (const float*)d_in[14];
    const float* log_k   = (const float*)d_in[15];

    char* ws = (char*)d_ws;
    uint2* recsR = (uint2*)ws;                                  // ESUB
    uint2* recsS = recsR + ESUB;                                // ESUB
    uint2* recsA = recsS + ESUB;                                // EALL
    float* v     = (float*)(recsA + EALL);                      // NRXN
    float* met_scale = v + NRXN;                                // NMET
    int* blockHistA = (int*)(met_scale + NMET);                 // NBUCK_M*NBM
    int* blockHistS = blockHistA + (size_t)NBUCK_M * NBM;       // NBUCK_M*NBM
    int* blockHistR = blockHistS + (size_t)NBUCK_M * NBM;       // NBUCK_R*NBR
    int* btotalA = blockHistR + (size_t)NBUCK_R * NBR;          // NBUCK_M
    int* bucketStartA = btotalA + NBUCK_M;                      // NBUCK_M+1
    int* btotalS = bucketStartA + NBUCK_M + 1;                  // NBUCK_M
    int* bucketStartS = btotalS + NBUCK_M;                      // NBUCK_M+1
    int* btotalR = bucketStartS + NBUCK_M + 1;                  // NBUCK_R
    int* bucketStartR = btotalR + NBUCK_R;                      // NBUCK_R+1
    float* out = (float*)d_out;

    dim3 blk(256);
    k_count_met<<<dim3(NBM), blk, 0, stream>>>(met_all, met_sub, blockHistA, blockHistS);
    k_count_rxn<<<dim3(NBR), blk, 0, stream>>>(rxn_sub, blockHistR);
    k_bscan_g<<<dim3(NBUCK_M), blk, 0, stream>>>(blockHistA, btotalA, NBM);
    k_bscan_g<<<dim3(NBUCK_M), blk, 0, stream>>>(blockHistS, btotalS, NBM);
    k_bscan_g<<<dim3(NBUCK_R), blk, 0, stream>>>(blockHistR, btotalR, NBR);
    k_bstart_g<<<dim3(1), dim3(1024), 0, stream>>>(btotalA, bucketStartA, NBUCK_M);
    k_bstart_g<<<dim3(1), dim3(1024), 0, stream>>>(btotalS, bucketStartS, NBUCK_M);
    k_bstart_g<<<dim3(1), dim3(1024), 0, stream>>>(btotalR, bucketStartR, NBUCK_R);
    k_rxn_scatter<<<dim3(NBR), blk, 0, stream>>>(
        rxn_sub, met_sub, sto_sub, blockHistR, bucketStartR, recsR);
    k_bucket_rxn<<<dim3(NBUCK_R), blk, 0, stream>>>(
        recsR, bucketStartR, x, sub_w1, sub_b1, sub_w2, sub_b2,
        rate_w1, rate_b1, rate_w2, rate_b2, log_k, v);
    k_cons_scatter<<<dim3(NBM), blk, 0, stream>>>(
        met_sub, rxn_sub, sto_sub, v, blockHistS, bucketStartS, recsS);
    k_baccum_tot<<<dim3(NBUCK_M), blk, 0, stream>>>(
        recsS, bucketStartS, x, met_scale);
    k_rscale_bucket<<<dim3(NBUCK_R), blk, 0, stream>>>(
        recsR, bucketStartR, met_scale, v);
    k_bscatter<<<dim3(NBM), blk, 0, stream>>>(
        met_all, rxn_all, sto_all, v, blockHistA, bucketStartA, recsA);
    k_baccum<<<dim3(NBUCK_M), blk, 0, stream>>>(recsA, bucketStartA, x, out);
}

// Round 9
// 197.906 us; speedup vs baseline: 1.1943x; 1.1943x over previous
//
#include <hip/hip_runtime.h>

#define NMET 200000
#define NRXN 400000
#define ESUB 800000
#define EALL 1600000

// met-bucket sort (consume + contrib): bucket = met >> 9, 512 mets/bucket
#define NBUCK_M 391                  // ceil(200000/512)
#define NBM 196                      // blocks for met counting/scatter
#define EBA 8192                     // met_all edges per block (196*8192 >= EALL)
#define EBS 4096                     // met_sub edges per block

// rxn-bucket sort (CSR build): bucket = rxn >> 9, 512 rxns/bucket
#define NBUCK_R 782                  // ceil(400000/512); 782*512 = 400384
#define NBR 1024                     // blocks for rxn counting/scatter
#define EBR 782                      // edges per block (1024*782 >= ESUB)
#define MET_MASK 0x3FFFF             // 18 bits (NMET < 262144)

// c_target = 1 + 0.5*sin(2*pi*100/1000) = 1.2938926261462366
#define C_TARGET 1.29389262614623664f
#define DT_C 0.01f
#define HOMEO_C 0.1f
#define LOG2_10 3.32192809488736235f

__device__ __forceinline__ float fast_tanh(float x) {
    float e = __expf(2.0f * x);
    return 1.0f - 2.0f * __builtin_amdgcn_rcpf(e + 1.0f);
}

// ---- 1a. met-bucket counts for contrib (A) and consume (S) -----------------
__global__ __launch_bounds__(256) void k_count_met(
    const int* __restrict__ met_all, const int* __restrict__ met_sub,
    int* __restrict__ blockHistA, int* __restrict__ blockHistS)
{
    __shared__ int hA[NBUCK_M];
    __shared__ int hS[NBUCK_M];
    int t = threadIdx.x;
    for (int b = t; b < NBUCK_M; b += 256) { hA[b] = 0; hS[b] = 0; }
    __syncthreads();
    int baseA = blockIdx.x * EBA;
    for (int i = t; i < EBA; i += 256) {
        int e = baseA + i;
        if (e < EALL) atomicAdd(&hA[met_all[e] >> 9], 1);
    }
    int baseS = blockIdx.x * EBS;
    for (int i = t; i < EBS; i += 256) {
        int e = baseS + i;
        if (e < ESUB) atomicAdd(&hS[met_sub[e] >> 9], 1);
    }
    __syncthreads();
    for (int b = t; b < NBUCK_M; b += 256) {
        blockHistA[(size_t)b * NBM + blockIdx.x] = hA[b];
        blockHistS[(size_t)b * NBM + blockIdx.x] = hS[b];
    }
}

// ---- 1b. rxn-bucket counts --------------------------------------------------
__global__ __launch_bounds__(256) void k_count_rxn(
    const int* __restrict__ rxn_sub, int* __restrict__ blockHistR)
{
    __shared__ int hR[NBUCK_R];
    int t = threadIdx.x;
    for (int b = t; b < NBUCK_R; b += 256) hR[b] = 0;
    __syncthreads();
    int base = blockIdx.x * EBR;
    for (int i = t; i < EBR; i += 256) {
        int e = base + i;
        if (e < ESUB) atomicAdd(&hR[rxn_sub[e] >> 9], 1);
    }
    __syncthreads();
    for (int b = t; b < NBUCK_R; b += 256)
        blockHistR[(size_t)b * NBR + blockIdx.x] = hR[b];
}

// ---- 2. generic per-bucket scan over nb block counts (in place) ------------
__global__ __launch_bounds__(256) void k_bscan_g(
    int* __restrict__ hist, int* __restrict__ total, int nb)
{
    __shared__ int lds[256];
    __shared__ int carry_s;
    int t = threadIdx.x;
    size_t base = (size_t)blockIdx.x * nb;
    if (t == 0) carry_s = 0;
    __syncthreads();
    for (int off0 = 0; off0 < nb; off0 += 256) {
        int i = off0 + t;
        int val = (i < nb) ? hist[base + i] : 0;
        lds[t] = val;
        __syncthreads();
        for (int off = 1; off < 256; off <<= 1) {
            int add = (t >= off) ? lds[t - off] : 0;
            __syncthreads();
            lds[t] += add;
            __syncthreads();
        }
        int incl = lds[t];
        int carry = carry_s;
        if (i < nb) hist[base + i] = carry + incl - val;
        __syncthreads();
        if (t == 255) carry_s = carry + incl;
        __syncthreads();
    }
    if (t == 0) total[blockIdx.x] = carry_s;
}

// ---- 3. generic one-block scan of bucket totals -> bucketStart -------------
__global__ __launch_bounds__(1024) void k_bstart_g(
    const int* __restrict__ total, int* __restrict__ start, int nbuck)
{
    __shared__ int lds[1024];
    int t = threadIdx.x;
    int val = (t < nbuck) ? total[t] : 0;
    lds[t] = val;
    __syncthreads();
    for (int off = 1; off < 1024; off <<= 1) {
        int add = (t >= off) ? lds[t - off] : 0;
        __syncthreads();
        lds[t] += add;
        __syncthreads();
    }
    if (t < nbuck) start[t] = lds[t] - val;
    if (t == 1023) start[nbuck] = lds[1023];
}

// ---- 4. scatter rxn records {met | rloc<<18, sto} into rxn buckets ---------
__global__ __launch_bounds__(256) void k_rxn_scatter(
    const int* __restrict__ rxn_sub, const int* __restrict__ met_sub,
    const float* __restrict__ sto_sub,
    const int* __restrict__ blockHistR, const int* __restrict__ bucketStartR,
    uint2* __restrict__ recsR)
{
    __shared__ int bbase[NBUCK_R];
    __shared__ int h[NBUCK_R];
    int t = threadIdx.x;
    for (int b = t; b < NBUCK_R; b += 256) {
        h[b] = 0;
        bbase[b] = bucketStartR[b] + blockHistR[(size_t)b * NBR + blockIdx.x];
    }
    __syncthreads();
    int base = blockIdx.x * EBR;
    for (int i = t; i < EBR; i += 256) {
        int e = base + i;
        if (e < ESUB) {
            int r = rxn_sub[e];
            int b = r >> 9;
            int rloc = r & 511;
            int slot = bbase[b] + atomicAdd(&h[b], 1);
            uint2 rec;
            rec.x = (unsigned)(met_sub[e] | (rloc << 18));
            rec.y = __float_as_uint(sto_sub[e]);
            recsR[slot] = rec;
        }
    }
}

// ---- 5. per-bucket CSR finalize: count rlocs, local scan, reorder ----------
// Produces recsC in true CSR order + cntG/offG (indexed directly by r).
__global__ __launch_bounds__(256) void k_csr_bucket(
    const uint2* __restrict__ recsR, const int* __restrict__ bucketStartR,
    int* __restrict__ cntG, int* __restrict__ offG, uint2* __restrict__ recsC)
{
    __shared__ int cnt[512];
    __shared__ int loff[512];
    __shared__ int pscan[256];
    __shared__ int rnk[512];
    int t = threadIdx.x;
    cnt[t] = 0; cnt[t + 256] = 0;
    rnk[t] = 0; rnk[t + 256] = 0;
    __syncthreads();

    int b = blockIdx.x;
    int s = bucketStartR[b], epos = bucketStartR[b + 1];
    for (int i = s + t; i < epos; i += 256)
        atomicAdd(&cnt[(recsR[i].x >> 18) & 511], 1);
    __syncthreads();

    // 512-wide exclusive scan via 256 pair-sums (Hillis-Steele)
    int c0 = cnt[2 * t], c1 = cnt[2 * t + 1];
    int ps = c0 + c1;
    pscan[t] = ps;
    __syncthreads();
    for (int off = 1; off < 256; off <<= 1) {
        int add = (t >= off) ? pscan[t - off] : 0;
        __syncthreads();
        pscan[t] += add;
        __syncthreads();
    }
    int excl = pscan[t] - ps;
    loff[2 * t] = excl;
    loff[2 * t + 1] = excl + c0;
    __syncthreads();

    int gb = b << 9;
    for (int j = t; j < 512; j += 256) {
        cntG[gb + j] = cnt[j];
        offG[gb + j] = s + loff[j];
    }

    for (int i = s + t; i < epos; i += 256) {
        uint2 rec = recsR[i];
        int rloc = (rec.x >> 18) & 511;
        int pos = loff[rloc] + atomicAdd(&rnk[rloc], 1);
        recsC[s + pos] = rec;
    }
}

// ---- 6. slot-parallel edge MLP over CSR-ordered records --------------------
__global__ __launch_bounds__(256) void k_msg2(
    const uint2* __restrict__ recsC, const float* __restrict__ x,
    const float* __restrict__ sub_w1, const float* __restrict__ sub_b1,
    const float* __restrict__ sub_w2,
    float4* __restrict__ msgA, float4* __restrict__ msgB,
    float* __restrict__ extS)
{
    __shared__ float sW1[128];
    __shared__ float sB1[64];
    __shared__ __align__(16) float sW2[512];
    int t = threadIdx.x;
    for (int i = t; i < 128; i += 256) sW1[i] = sub_w1[i];
    for (int i = t; i < 64;  i += 256) sB1[i] = sub_b1[i];
    for (int i = t; i < 512; i += 256) sW2[i] = sub_w2[i];
    __syncthreads();

    int i = blockIdx.x * 256 + t;
    if (i >= ESUB) return;
    uint2 rec = recsC[i];                 // contiguous 8B read
    int m = rec.x & MET_MASK;
    float st = __uint_as_float(rec.y);
    float c  = x[(size_t)m * 8 + 3];      // random, L2/L3-resident
    float ex = x[(size_t)m * 8 + 4];

    float m0 = 0.f, m1 = 0.f, m2 = 0.f, m3 = 0.f;
    float m4 = 0.f, m5 = 0.f, m6 = 0.f, m7 = 0.f;
    #pragma unroll 8
    for (int j = 0; j < 64; ++j) {
        float z = fmaf(c, sW1[j], fmaf(st, sW1[64 + j], sB1[j]));
        float th = fast_tanh(z);
        float4 wa = *(const float4*)&sW2[j * 8];
        float4 wb = *(const float4*)&sW2[j * 8 + 4];
        m0 = fmaf(th, wa.x, m0); m1 = fmaf(th, wa.y, m1);
        m2 = fmaf(th, wa.z, m2); m3 = fmaf(th, wa.w, m3);
        m4 = fmaf(th, wb.x, m4); m5 = fmaf(th, wb.y, m5);
        m6 = fmaf(th, wb.z, m6); m7 = fmaf(th, wb.w, m7);
    }
    msgA[i] = make_float4(m0, m1, m2, m3);
    msgB[i] = make_float4(m4, m5, m6, m7);
    extS[i] = ex;
}

// ---- 7. per-reaction: contiguous msg segment sum, rate MLP -> v ------------
__global__ __launch_bounds__(256) void k_rxn3(
    const int* __restrict__ cntG, const int* __restrict__ offG,
    const float4* __restrict__ msgA, const float4* __restrict__ msgB,
    const float* __restrict__ extS,
    const float* __restrict__ sub_b2,
    const float* __restrict__ rate_w1, const float* __restrict__ rate_b1,
    const float* __restrict__ rate_w2, const float* __restrict__ rate_b2,
    const float* __restrict__ log_k, float* __restrict__ v)
{
    __shared__ __align__(16) float sR1[512];
    __shared__ float sRB1[64];
    __shared__ float sR2[64];
    __shared__ float sB2[8];
    __shared__ float sRB2;
    int t = threadIdx.x;
    for (int i = t; i < 512; i += 256) sR1[i] = rate_w1[i];
    if (t < 64) { sRB1[t] = rate_b1[t]; sR2[t] = rate_w2[t]; }
    if (t < 8) sB2[t] = sub_b2[t];
    if (t == 64) sRB2 = rate_b2[0];
    __syncthreads();

    int r = blockIdx.x * 256 + t;
    if (r >= NRXN) return;
    int n = cntG[r];
    int base = offG[r];
    float fn = (float)n;

    float h0 = fn * sB2[0], h1 = fn * sB2[1], h2 = fn * sB2[2], h3 = fn * sB2[3];
    float h4 = fn * sB2[4], h5 = fn * sB2[5], h6 = fn * sB2[6], h7 = fn * sB2[7];
    float exs = 0.f;
    for (int i = 0; i < n; ++i) {
        float4 a = msgA[base + i];
        float4 b = msgB[base + i];
        h0 += a.x; h1 += a.y; h2 += a.z; h3 += a.w;
        h4 += b.x; h5 += b.y; h6 += b.z; h7 += b.w;
        exs += extS[base + i];
    }

    float acc = sRB2;
    #pragma unroll 4
    for (int j = 0; j < 64; ++j) {
        float z = sRB1[j];
        z = fmaf(h0, sR1[j],       z);
        z = fmaf(h1, sR1[64 + j],  z);
        z = fmaf(h2, sR1[128 + j], z);
        z = fmaf(h3, sR1[192 + j], z);
        z = fmaf(h4, sR1[256 + j], z);
        z = fmaf(h5, sR1[320 + j], z);
        z = fmaf(h6, sR1[384 + j], z);
        z = fmaf(h7, sR1[448 + j], z);
        acc = fmaf(fast_tanh(z), sR2[j], acc);
    }
    float nmax = fmaxf(fn, 1.0f);
    float ext_mean = 2.0f * exs * __builtin_amdgcn_rcpf(nmax);
    float kk = exp2f(log_k[r] * LOG2_10);
    v[r] = kk * ext_mean * acc;
}

// ---- 8. consume bucket-scatter (edge order, pre-limit v) -------------------
__global__ __launch_bounds__(256) void k_cons_scatter(
    const int* __restrict__ met_sub, const int* __restrict__ rxn_sub,
    const float* __restrict__ sto_sub, const float* __restrict__ v,
    const int* __restrict__ blockHistS, const int* __restrict__ bucketStartS,
    uint2* __restrict__ recsS)
{
    __shared__ int h[NBUCK_M];
    __shared__ int bbase[NBUCK_M];
    int t = threadIdx.x;
    for (int b = t; b < NBUCK_M; b += 256) {
        h[b] = 0;
        bbase[b] = bucketStartS[b] + blockHistS[(size_t)b * NBM + blockIdx.x];
    }
    __syncthreads();
    int base = blockIdx.x * EBS;
    for (int i = t; i < EBS; i += 256) {
        int e = base + i;
        if (e < ESUB) {
            int m = met_sub[e];
            int b = m >> 9;
            float val = sto_sub[e] * v[rxn_sub[e]] * DT_C;
            int r = atomicAdd(&h[b], 1);
            uint2 rec;
            rec.x = (unsigned)m;
            rec.y = __float_as_uint(val);
            recsS[bbase[b] + r] = rec;
        }
    }
}

// ---- 9. per-bucket accumulate total -> met_scale ---------------------------
__global__ __launch_bounds__(256) void k_baccum_tot(
    const uint2* __restrict__ recsS, const int* __restrict__ bucketStartS,
    const float* __restrict__ x, float* __restrict__ met_scale)
{
    __shared__ float acc[512];
    int b = blockIdx.x;
    int t = threadIdx.x;
    for (int j = t; j < 512; j += 256) acc[j] = 0.f;
    __syncthreads();
    int s = bucketStartS[b], epos = bucketStartS[b + 1];
    for (int i = s + t; i < epos; i += 256) {
        uint2 rec = recsS[i];
        atomicAdd(&acc[rec.x & 511], __uint_as_float(rec.y));
    }
    __syncthreads();
    int mbase = b << 9;
    for (int j = t; j < 512; j += 256) {
        int m = mbase + j;
        if (m < NMET) {
            float tot = acc[j];
            float ms = 1.0f;
            if (tot > 1e-12f) ms = fminf(x[(size_t)m * 8 + 3] / tot, 1.0f);
            met_scale[m] = ms;
        }
    }
}

// ---- 10. per-reaction min over CSR records + v scale -----------------------
__global__ __launch_bounds__(256) void k_rscale(
    const int* __restrict__ cntG, const int* __restrict__ offG,
    const uint2* __restrict__ recsC, const float* __restrict__ met_scale,
    float* __restrict__ v)
{
    int r = blockIdx.x * 256 + threadIdx.x;
    if (r >= NRXN) return;
    int n = cntG[r];
    int base = offG[r];
    float ms = 1.0f;
    for (int i = 0; i < n; ++i)
        ms = fminf(ms, met_scale[recsC[base + i].x & MET_MASK]);
    v[r] *= ms;
}

// ---- 11. contrib bucket-scatter (edge order, post-limit v) -----------------
__global__ __launch_bounds__(256) void k_bscatter(
    const int* __restrict__ met_all, const int* __restrict__ rxn_all,
    const float* __restrict__ sto_all, const float* __restrict__ v,
    const int* __restrict__ blockHistA, const int* __restrict__ bucketStartA,
    uint2* __restrict__ recsA)
{
    __shared__ int h[NBUCK_M];
    __shared__ int bbase[NBUCK_M];
    int t = threadIdx.x;
    for (int b = t; b < NBUCK_M; b += 256) {
        h[b] = 0;
        bbase[b] = bucketStartA[b] + blockHistA[(size_t)b * NBM + blockIdx.x];
    }
    __syncthreads();
    int base = blockIdx.x * EBA;
    for (int i = t; i < EBA; i += 256) {
        int e = base + i;
        if (e < EALL) {
            int m = met_all[e];
            int b = m >> 9;
            float val = sto_all[e] * v[rxn_all[e]];
            int r = atomicAdd(&h[b], 1);
            uint2 rec;
            rec.x = (unsigned)m;
            rec.y = __float_as_uint(val);
            recsA[bbase[b] + r] = rec;
        }
    }
}

// ---- 12. per-bucket accumulate + homeostasis epilogue ----------------------
__global__ __launch_bounds__(256) void k_baccum(
    const uint2* __restrict__ recsA, const int* __restrict__ bucketStartA,
    const float* __restrict__ x, float* __restrict__ out)
{
    __shared__ float acc[512];
    int b = blockIdx.x;
    int t = threadIdx.x;
    for (int j = t; j < 512; j += 256) acc[j] = 0.f;
    __syncthreads();
    int s = bucketStartA[b], epos = bucketStartA[b + 1];
    for (int i = s + t; i < epos; i += 256) {
        uint2 rec = recsA[i];
        atomicAdd(&acc[rec.x & 511], __uint_as_float(rec.y));
    }
    __syncthreads();
    int mbase = b << 9;
    for (int j = t; j < 512; j += 256) {
        int m = mbase + j;
        if (m < NMET) {
            float c = x[(size_t)m * 8 + 3];
            out[m] = acc[j] - HOMEO_C * (c - C_TARGET);
        }
    }
}

extern "C" void kernel_launch(void* const* d_in, const int* in_sizes, int n_in,
                              void* d_out, int out_size, void* d_ws, size_t ws_size,
                              hipStream_t stream) {
    const float* x       = (const float*)d_in[0];
    const int*   met_sub = (const int*)  d_in[1];
    const int*   rxn_sub = (const int*)  d_in[2];
    const float* sto_sub = (const float*)d_in[3];
    const int*   met_all = (const int*)  d_in[4];
    const int*   rxn_all = (const int*)  d_in[5];
    const float* sto_all = (const float*)d_in[6];
    const float* sub_w1  = (const float*)d_in[7];
    const float* sub_b1  = (const float*)d_in[8];
    const float* sub_w2  = (const float*)d_in[9];
    const float* sub_b2  = (const float*)d_in[10];
    const float* rate_w1 = (const float*)d_in[11];
    const float* rate_b1 = (const float*)d_in[12];
    const float* rate_w2 = (const float*)d_in[13];
    const float* rate_b2 = (const float*)d_in[14];
    const float* log_k   = (const float*)d_in[15];

    char* ws = (char*)d_ws;
    float4* msgA  = (float4*)ws;                                // ESUB
    float4* msgB  = msgA + ESUB;                                // ESUB
    uint2*  recsR = (uint2*)(msgB + ESUB);                      // ESUB
    uint2*  recsC = recsR + ESUB;                               // ESUB
    uint2*  recsS = recsC + ESUB;                               // ESUB
    uint2*  recsA = recsS + ESUB;                               // EALL
    float*  extS  = (float*)(recsA + EALL);                     // ESUB
    float*  v     = extS + ESUB;                                // NRXN
    float*  met_scale = v + NRXN;                               // NMET
    int* cntG = (int*)(met_scale + NMET);                       // NBUCK_R*512
    int* offG = cntG + (size_t)NBUCK_R * 512;                   // NBUCK_R*512
    int* blockHistA = offG + (size_t)NBUCK_R * 512;             // NBUCK_M*NBM
    int* blockHistS = blockHistA + (size_t)NBUCK_M * NBM;       // NBUCK_M*NBM
    int* blockHistR = blockHistS + (size_t)NBUCK_M * NBM;       // NBUCK_R*NBR
    int* btotalA = blockHistR + (size_t)NBUCK_R * NBR;          // NBUCK_M
    int* bucketStartA = btotalA + NBUCK_M;                      // NBUCK_M+1
    int* btotalS = bucketStartA + NBUCK_M + 1;                  // NBUCK_M
    int* bucketStartS = btotalS + NBUCK_M;                      // NBUCK_M+1
    int* btotalR = bucketStartS + NBUCK_M + 1;                  // NBUCK_R
    int* bucketStartR = btotalR + NBUCK_R;                      // NBUCK_R+1
    float* out = (float*)d_out;

    dim3 blk(256);
    k_count_met<<<dim3(NBM), blk, 0, stream>>>(met_all, met_sub, blockHistA, blockHistS);
    k_count_rxn<<<dim3(NBR), blk, 0, stream>>>(rxn_sub, blockHistR);
    k_bscan_g<<<dim3(NBUCK_M), blk, 0, stream>>>(blockHistA, btotalA, NBM);
    k_bscan_g<<<dim3(NBUCK_M), blk, 0, stream>>>(blockHistS, btotalS, NBM);
    k_bscan_g<<<dim3(NBUCK_R), blk, 0, stream>>>(blockHistR, btotalR, NBR);
    k_bstart_g<<<dim3(1), dim3(1024), 0, stream>>>(btotalA, bucketStartA, NBUCK_M);
    k_bstart_g<<<dim3(1), dim3(1024), 0, stream>>>(btotalS, bucketStartS, NBUCK_M);
    k_bstart_g<<<dim3(1), dim3(1024), 0, stream>>>(btotalR, bucketStartR, NBUCK_R);
    k_rxn_scatter<<<dim3(NBR), blk, 0, stream>>>(
        rxn_sub, met_sub, sto_sub, blockHistR, bucketStartR, recsR);
    k_csr_bucket<<<dim3(NBUCK_R), blk, 0, stream>>>(
        recsR, bucketStartR, cntG, offG, recsC);
    k_msg2<<<dim3((ESUB + 255) / 256), blk, 0, stream>>>(
        recsC, x, sub_w1, sub_b1, sub_w2, msgA, msgB, extS);
    k_rxn3<<<dim3((NRXN + 255) / 256), blk, 0, stream>>>(
        cntG, offG, msgA, msgB, extS, sub_b2,
        rate_w1, rate_b1, rate_w2, rate_b2, log_k, v);
    k_cons_scatter<<<dim3(NBM), blk, 0, stream>>>(
        met_sub, rxn_sub, sto_sub, v, blockHistS, bucketStartS, recsS);
    k_baccum_tot<<<dim3(NBUCK_M), blk, 0, stream>>>(
        recsS, bucketStartS, x, met_scale);
    k_rscale<<<dim3((NRXN + 255) / 256), blk, 0, stream>>>(
        cntG, offG, recsC, met_scale, v);
    k_bscatter<<<dim3(NBM), blk, 0, stream>>>(
        met_all, rxn_all, sto_all, v, blockHistA, bucketStartA, recsA);
    k_baccum<<<dim3(NBUCK_M), blk, 0, stream>>>(recsA, bucketStartA, x, out);
}

// Round 10
// 190.604 us; speedup vs baseline: 1.2401x; 1.0383x over previous
//
#include <hip/hip_runtime.h>

#define NMET 200000
#define NRXN 400000
#define ESUB 800000
#define EALL 1600000

// met-bucket sort (consume + contrib): bucket = met >> 9, 512 mets/bucket
#define NBUCK_M 391                  // ceil(200000/512)
#define NBM 392                      // blocks for met counting/scatter
#define EBA 4096                     // met_all edges per block (392*4096 >= EALL)
#define EBS 2048                     // met_sub edges per block (392*2048 >= ESUB)

// rxn-bucket sort (CSR build): bucket = rxn >> 9, 512 rxns/bucket
#define NBUCK_R 782                  // ceil(400000/512); 782*512 = 400384
#define NBR 1024                     // blocks for rxn counting/scatter
#define EBR 782                      // edges per block (1024*782 >= ESUB)
#define MET_MASK 0x3FFFF             // 18 bits (NMET < 262144)

// c_target = 1 + 0.5*sin(2*pi*100/1000) = 1.2938926261462366
#define C_TARGET 1.29389262614623664f
#define DT_C 0.01f
#define HOMEO_C 0.1f
#define LOG2_10 3.32192809488736235f

__device__ __forceinline__ float fast_tanh(float x) {
    float e = __expf(2.0f * x);
    return 1.0f - 2.0f * __builtin_amdgcn_rcpf(e + 1.0f);
}

// ---- 1a. met-bucket counts for contrib (A) and consume (S) -----------------
__global__ __launch_bounds__(512) void k_count_met(
    const int* __restrict__ met_all, const int* __restrict__ met_sub,
    int* __restrict__ blockHistA, int* __restrict__ blockHistS)
{
    __shared__ int hA[NBUCK_M];
    __shared__ int hS[NBUCK_M];
    int t = threadIdx.x;
    for (int b = t; b < NBUCK_M; b += 512) { hA[b] = 0; hS[b] = 0; }
    __syncthreads();
    int baseA = blockIdx.x * EBA;
    for (int i = t; i < EBA; i += 512) {
        int e = baseA + i;
        if (e < EALL) atomicAdd(&hA[met_all[e] >> 9], 1);
    }
    int baseS = blockIdx.x * EBS;
    for (int i = t; i < EBS; i += 512) {
        int e = baseS + i;
        if (e < ESUB) atomicAdd(&hS[met_sub[e] >> 9], 1);
    }
    __syncthreads();
    for (int b = t; b < NBUCK_M; b += 512) {
        blockHistA[(size_t)b * NBM + blockIdx.x] = hA[b];
        blockHistS[(size_t)b * NBM + blockIdx.x] = hS[b];
    }
}

// ---- 1b. rxn-bucket counts --------------------------------------------------
__global__ __launch_bounds__(256) void k_count_rxn(
    const int* __restrict__ rxn_sub, int* __restrict__ blockHistR)
{
    __shared__ int hR[NBUCK_R];
    int t = threadIdx.x;
    for (int b = t; b < NBUCK_R; b += 256) hR[b] = 0;
    __syncthreads();
    int base = blockIdx.x * EBR;
    for (int i = t; i < EBR; i += 256) {
        int e = base + i;
        if (e < ESUB) atomicAdd(&hR[rxn_sub[e] >> 9], 1);
    }
    __syncthreads();
    for (int b = t; b < NBUCK_R; b += 256)
        blockHistR[(size_t)b * NBR + blockIdx.x] = hR[b];
}

// ---- 2. generic per-bucket scan over nb block counts (in place) ------------
__global__ __launch_bounds__(256) void k_bscan_g(
    int* __restrict__ hist, int* __restrict__ total, int nb)
{
    __shared__ int lds[256];
    __shared__ int carry_s;
    int t = threadIdx.x;
    size_t base = (size_t)blockIdx.x * nb;
    if (t == 0) carry_s = 0;
    __syncthreads();
    for (int off0 = 0; off0 < nb; off0 += 256) {
        int i = off0 + t;
        int val = (i < nb) ? hist[base + i] : 0;
        lds[t] = val;
        __syncthreads();
        for (int off = 1; off < 256; off <<= 1) {
            int add = (t >= off) ? lds[t - off] : 0;
            __syncthreads();
            lds[t] += add;
            __syncthreads();
        }
        int incl = lds[t];
        int carry = carry_s;
        if (i < nb) hist[base + i] = carry + incl - val;
        __syncthreads();
        if (t == 255) carry_s = carry + incl;
        __syncthreads();
    }
    if (t == 0) total[blockIdx.x] = carry_s;
}

// ---- 3. generic one-block scan of bucket totals -> bucketStart -------------
__global__ __launch_bounds__(1024) void k_bstart_g(
    const int* __restrict__ total, int* __restrict__ start, int nbuck)
{
    __shared__ int lds[1024];
    int t = threadIdx.x;
    int val = (t < nbuck) ? total[t] : 0;
    lds[t] = val;
    __syncthreads();
    for (int off = 1; off < 1024; off <<= 1) {
        int add = (t >= off) ? lds[t - off] : 0;
        __syncthreads();
        lds[t] += add;
        __syncthreads();
    }
    if (t < nbuck) start[t] = lds[t] - val;
    if (t == 1023) start[nbuck] = lds[1023];
}

// ---- 4. scatter rxn records {met | rloc<<18, sto} into rxn buckets ---------
__global__ __launch_bounds__(256) void k_rxn_scatter(
    const int* __restrict__ rxn_sub, const int* __restrict__ met_sub,
    const float* __restrict__ sto_sub,
    const int* __restrict__ blockHistR, const int* __restrict__ bucketStartR,
    uint2* __restrict__ recsR)
{
    __shared__ int bbase[NBUCK_R];
    __shared__ int h[NBUCK_R];
    int t = threadIdx.x;
    for (int b = t; b < NBUCK_R; b += 256) {
        h[b] = 0;
        bbase[b] = bucketStartR[b] + blockHistR[(size_t)b * NBR + blockIdx.x];
    }
    __syncthreads();
    int base = blockIdx.x * EBR;
    for (int i = t; i < EBR; i += 256) {
        int e = base + i;
        if (e < ESUB) {
            int r = rxn_sub[e];
            int b = r >> 9;
            int rloc = r & 511;
            int slot = bbase[b] + atomicAdd(&h[b], 1);
            uint2 rec;
            rec.x = (unsigned)(met_sub[e] | (rloc << 18));
            rec.y = __float_as_uint(sto_sub[e]);
            recsR[slot] = rec;
        }
    }
}

// ---- 5. per-bucket CSR finalize: count rlocs, local scan, reorder ----------
__global__ __launch_bounds__(256) void k_csr_bucket(
    const uint2* __restrict__ recsR, const int* __restrict__ bucketStartR,
    int* __restrict__ cntG, int* __restrict__ offG, uint2* __restrict__ recsC)
{
    __shared__ int cnt[512];
    __shared__ int loff[512];
    __shared__ int pscan[256];
    __shared__ int rnk[512];
    int t = threadIdx.x;
    cnt[t] = 0; cnt[t + 256] = 0;
    rnk[t] = 0; rnk[t + 256] = 0;
    __syncthreads();

    int b = blockIdx.x;
    int s = bucketStartR[b], epos = bucketStartR[b + 1];
    for (int i = s + t; i < epos; i += 256)
        atomicAdd(&cnt[(recsR[i].x >> 18) & 511], 1);
    __syncthreads();

    int c0 = cnt[2 * t], c1 = cnt[2 * t + 1];
    int ps = c0 + c1;
    pscan[t] = ps;
    __syncthreads();
    for (int off = 1; off < 256; off <<= 1) {
        int add = (t >= off) ? pscan[t - off] : 0;
        __syncthreads();
        pscan[t] += add;
        __syncthreads();
    }
    int excl = pscan[t] - ps;
    loff[2 * t] = excl;
    loff[2 * t + 1] = excl + c0;
    __syncthreads();

    int gb = b << 9;
    for (int j = t; j < 512; j += 256) {
        cntG[gb + j] = cnt[j];
        offG[gb + j] = s + loff[j];
    }

    for (int i = s + t; i < epos; i += 256) {
        uint2 rec = recsR[i];
        int rloc = (rec.x >> 18) & 511;
        int pos = loff[rloc] + atomicAdd(&rnk[rloc], 1);
        recsC[s + pos] = rec;
    }
}

// ---- 6. slot-parallel edge MLP over CSR-ordered records --------------------
__global__ __launch_bounds__(256) void k_msg2(
    const uint2* __restrict__ recsC, const float* __restrict__ x,
    const float* __restrict__ sub_w1, const float* __restrict__ sub_b1,
    const float* __restrict__ sub_w2,
    float4* __restrict__ msgA, float4* __restrict__ msgB,
    float* __restrict__ extS)
{
    __shared__ float sW1[128];
    __shared__ float sB1[64];
    __shared__ __align__(16) float sW2[512];
    int t = threadIdx.x;
    for (int i = t; i < 128; i += 256) sW1[i] = sub_w1[i];
    for (int i = t; i < 64;  i += 256) sB1[i] = sub_b1[i];
    for (int i = t; i < 512; i += 256) sW2[i] = sub_w2[i];
    __syncthreads();

    int i = blockIdx.x * 256 + t;
    if (i >= ESUB) return;
    uint2 rec = recsC[i];
    int m = rec.x & MET_MASK;
    float st = __uint_as_float(rec.y);
    float c  = x[(size_t)m * 8 + 3];
    float ex = x[(size_t)m * 8 + 4];

    float m0 = 0.f, m1 = 0.f, m2 = 0.f, m3 = 0.f;
    float m4 = 0.f, m5 = 0.f, m6 = 0.f, m7 = 0.f;
    #pragma unroll 8
    for (int j = 0; j < 64; ++j) {
        float z = fmaf(c, sW1[j], fmaf(st, sW1[64 + j], sB1[j]));
        float th = fast_tanh(z);
        float4 wa = *(const float4*)&sW2[j * 8];
        float4 wb = *(const float4*)&sW2[j * 8 + 4];
        m0 = fmaf(th, wa.x, m0); m1 = fmaf(th, wa.y, m1);
        m2 = fmaf(th, wa.z, m2); m3 = fmaf(th, wa.w, m3);
        m4 = fmaf(th, wb.x, m4); m5 = fmaf(th, wb.y, m5);
        m6 = fmaf(th, wb.z, m6); m7 = fmaf(th, wb.w, m7);
    }
    msgA[i] = make_float4(m0, m1, m2, m3);
    msgB[i] = make_float4(m4, m5, m6, m7);
    extS[i] = ex;
}

// ---- 7. per-reaction: contiguous msg segment sum, rate MLP -> v ------------
__global__ __launch_bounds__(256) void k_rxn3(
    const int* __restrict__ cntG, const int* __restrict__ offG,
    const float4* __restrict__ msgA, const float4* __restrict__ msgB,
    const float* __restrict__ extS,
    const float* __restrict__ sub_b2,
    const float* __restrict__ rate_w1, const float* __restrict__ rate_b1,
    const float* __restrict__ rate_w2, const float* __restrict__ rate_b2,
    const float* __restrict__ log_k, float* __restrict__ v)
{
    __shared__ __align__(16) float sR1[512];
    __shared__ float sRB1[64];
    __shared__ float sR2[64];
    __shared__ float sB2[8];
    __shared__ float sRB2;
    int t = threadIdx.x;
    for (int i = t; i < 512; i += 256) sR1[i] = rate_w1[i];
    if (t < 64) { sRB1[t] = rate_b1[t]; sR2[t] = rate_w2[t]; }
    if (t < 8) sB2[t] = sub_b2[t];
    if (t == 64) sRB2 = rate_b2[0];
    __syncthreads();

    int r = blockIdx.x * 256 + t;
    if (r >= NRXN) return;
    int n = cntG[r];
    int base = offG[r];
    float fn = (float)n;

    float h0 = fn * sB2[0], h1 = fn * sB2[1], h2 = fn * sB2[2], h3 = fn * sB2[3];
    float h4 = fn * sB2[4], h5 = fn * sB2[5], h6 = fn * sB2[6], h7 = fn * sB2[7];
    float exs = 0.f;
    for (int i = 0; i < n; ++i) {
        float4 a = msgA[base + i];
        float4 b = msgB[base + i];
        h0 += a.x; h1 += a.y; h2 += a.z; h3 += a.w;
        h4 += b.x; h5 += b.y; h6 += b.z; h7 += b.w;
        exs += extS[base + i];
    }

    float acc = sRB2;
    #pragma unroll 4
    for (int j = 0; j < 64; ++j) {
        float z = sRB1[j];
        z = fmaf(h0, sR1[j],       z);
        z = fmaf(h1, sR1[64 + j],  z);
        z = fmaf(h2, sR1[128 + j], z);
        z = fmaf(h3, sR1[192 + j], z);
        z = fmaf(h4, sR1[256 + j], z);
        z = fmaf(h5, sR1[320 + j], z);
        z = fmaf(h6, sR1[384 + j], z);
        z = fmaf(h7, sR1[448 + j], z);
        acc = fmaf(fast_tanh(z), sR2[j], acc);
    }
    float nmax = fmaxf(fn, 1.0f);
    float ext_mean = 2.0f * exs * __builtin_amdgcn_rcpf(nmax);
    float kk = exp2f(log_k[r] * LOG2_10);
    v[r] = kk * ext_mean * acc;
}

// ---- 8. consume bucket-scatter (edge order, pre-limit v) -------------------
__global__ __launch_bounds__(512) void k_cons_scatter(
    const int* __restrict__ met_sub, const int* __restrict__ rxn_sub,
    const float* __restrict__ sto_sub, const float* __restrict__ v,
    const int* __restrict__ blockHistS, const int* __restrict__ bucketStartS,
    uint2* __restrict__ recsS)
{
    __shared__ int h[NBUCK_M];
    __shared__ int bbase[NBUCK_M];
    int t = threadIdx.x;
    for (int b = t; b < NBUCK_M; b += 512) {
        h[b] = 0;
        bbase[b] = bucketStartS[b] + blockHistS[(size_t)b * NBM + blockIdx.x];
    }
    __syncthreads();
    int base = blockIdx.x * EBS;
    for (int i = t; i < EBS; i += 512) {
        int e = base + i;
        if (e < ESUB) {
            int m = met_sub[e];
            int b = m >> 9;
            float val = sto_sub[e] * v[rxn_sub[e]] * DT_C;
            int r = atomicAdd(&h[b], 1);
            uint2 rec;
            rec.x = (unsigned)m;
            rec.y = __float_as_uint(val);
            recsS[bbase[b] + r] = rec;
        }
    }
}

// ---- 9. per-bucket accumulate total -> met_scale ---------------------------
__global__ __launch_bounds__(512) void k_baccum_tot(
    const uint2* __restrict__ recsS, const int* __restrict__ bucketStartS,
    const float* __restrict__ x, float* __restrict__ met_scale)
{
    __shared__ float acc[512];
    int b = blockIdx.x;
    int t = threadIdx.x;
    acc[t] = 0.f;
    __syncthreads();
    int s = bucketStartS[b], epos = bucketStartS[b + 1];
    for (int i = s + t; i < epos; i += 512) {
        uint2 rec = recsS[i];
        atomicAdd(&acc[rec.x & 511], __uint_as_float(rec.y));
    }
    __syncthreads();
    int m = (b << 9) + t;
    if (m < NMET) {
        float tot = acc[t];
        float ms = 1.0f;
        if (tot > 1e-12f) ms = fminf(x[(size_t)m * 8 + 3] / tot, 1.0f);
        met_scale[m] = ms;
    }
}

// ---- 10. per-reaction min over CSR records + v scale -----------------------
__global__ __launch_bounds__(256) void k_rscale(
    const int* __restrict__ cntG, const int* __restrict__ offG,
    const uint2* __restrict__ recsC, const float* __restrict__ met_scale,
    float* __restrict__ v)
{
    int r = blockIdx.x * 256 + threadIdx.x;
    if (r >= NRXN) return;
    int n = cntG[r];
    int base = offG[r];
    float ms = 1.0f;
    for (int i = 0; i < n; ++i)
        ms = fminf(ms, met_scale[recsC[base + i].x & MET_MASK]);
    v[r] *= ms;
}

// ---- 11. contrib bucket-scatter (edge order, post-limit v) -----------------
__global__ __launch_bounds__(512) void k_bscatter(
    const int* __restrict__ met_all, const int* __restrict__ rxn_all,
    const float* __restrict__ sto_all, const float* __restrict__ v,
    const int* __restrict__ blockHistA, const int* __restrict__ bucketStartA,
    uint2* __restrict__ recsA)
{
    __shared__ int h[NBUCK_M];
    __shared__ int bbase[NBUCK_M];
    int t = threadIdx.x;
    for (int b = t; b < NBUCK_M; b += 512) {
        h[b] = 0;
        bbase[b] = bucketStartA[b] + blockHistA[(size_t)b * NBM + blockIdx.x];
    }
    __syncthreads();
    int base = blockIdx.x * EBA;
    for (int i = t; i < EBA; i += 512) {
        int e = base + i;
        if (e < EALL) {
            int m = met_all[e];
            int b = m >> 9;
            float val = sto_all[e] * v[rxn_all[e]];
            int r = atomicAdd(&h[b], 1);
            uint2 rec;
            rec.x = (unsigned)m;
            rec.y = __float_as_uint(val);
            recsA[bbase[b] + r] = rec;
        }
    }
}

// ---- 12. per-bucket accumulate + homeostasis epilogue ----------------------
__global__ __launch_bounds__(512) void k_baccum(
    const uint2* __restrict__ recsA, const int* __restrict__ bucketStartA,
    const float* __restrict__ x, float* __restrict__ out)
{
    __shared__ float acc[512];
    int b = blockIdx.x;
    int t = threadIdx.x;
    acc[t] = 0.f;
    __syncthreads();
    int s = bucketStartA[b], epos = bucketStartA[b + 1];
    for (int i = s + t; i < epos; i += 512) {
        uint2 rec = recsA[i];
        atomicAdd(&acc[rec.x & 511], __uint_as_float(rec.y));
    }
    __syncthreads();
    int m = (b << 9) + t;
    if (m < NMET) {
        float c = x[(size_t)m * 8 + 3];
        out[m] = acc[t] - HOMEO_C * (c - C_TARGET);
    }
}

extern "C" void kernel_launch(void* const* d_in, const int* in_sizes, int n_in,
                              void* d_out, int out_size, void* d_ws, size_t ws_size,
                              hipStream_t stream) {
    const float* x       = (const float*)d_in[0];
    const int*   met_sub = (const int*)  d_in[1];
    const int*   rxn_sub = (const int*)  d_in[2];
    const float* sto_sub = (const float*)d_in[3];
    const int*   met_all = (const int*)  d_in[4];
    const int*   rxn_all = (const int*)  d_in[5];
    const float* sto_all = (const float*)d_in[6];
    const float* sub_w1  = (const float*)d_in[7];
    const float* sub_b1  = (const float*)d_in[8];
    const float* sub_w2  = (const float*)d_in[9];
    const float* sub_b2  = (const float*)d_in[10];
    const float* rate_w1 = (const float*)d_in[11];
    const float* rate_b1 = (const float*)d_in[12];
    const float* rate_w2 = (const float*)d_in[13];
    const float* rate_b2 = (const float*)d_in[14];
    const float* log_k   = (const float*)d_in[15];

    char* ws = (char*)d_ws;
    float4* msgA  = (float4*)ws;                                // ESUB
    float4* msgB  = msgA + ESUB;                                // ESUB
    uint2*  recsR = (uint2*)(msgB + ESUB);                      // ESUB
    uint2*  recsC = recsR + ESUB;                               // ESUB
    uint2*  recsS = recsC + ESUB;                               // ESUB
    uint2*  recsA = recsS + ESUB;                               // EALL
    float*  extS  = (float*)(recsA + EALL);                     // ESUB
    float*  v     = extS + ESUB;                                // NRXN
    float*  met_scale = v + NRXN;                               // NMET
    int* cntG = (int*)(met_scale + NMET);                       // NBUCK_R*512
    int* offG = cntG + (size_t)NBUCK_R * 512;                   // NBUCK_R*512
    int* blockHistA = offG + (size_t)NBUCK_R * 512;             // NBUCK_M*NBM
    int* blockHistS = blockHistA + (size_t)NBUCK_M * NBM;       // NBUCK_M*NBM
    int* blockHistR = blockHistS + (size_t)NBUCK_M * NBM;       // NBUCK_R*NBR
    int* btotalA = blockHistR + (size_t)NBUCK_R * NBR;          // NBUCK_M
    int* bucketStartA = btotalA + NBUCK_M;                      // NBUCK_M+1
    int* btotalS = bucketStartA + NBUCK_M + 1;                  // NBUCK_M
    int* bucketStartS = btotalS + NBUCK_M;                      // NBUCK_M+1
    int* btotalR = bucketStartS + NBUCK_M + 1;                  // NBUCK_R
    int* bucketStartR = btotalR + NBUCK_R;                      // NBUCK_R+1
    float* out = (float*)d_out;

    dim3 blk(256);
    dim3 blk512(512);
    k_count_met<<<dim3(NBM), blk512, 0, stream>>>(met_all, met_sub, blockHistA, blockHistS);
    k_count_rxn<<<dim3(NBR), blk, 0, stream>>>(rxn_sub, blockHistR);
    k_bscan_g<<<dim3(NBUCK_M), blk, 0, stream>>>(blockHistA, btotalA, NBM);
    k_bscan_g<<<dim3(NBUCK_M), blk, 0, stream>>>(blockHistS, btotalS, NBM);
    k_bscan_g<<<dim3(NBUCK_R), blk, 0, stream>>>(blockHistR, btotalR, NBR);
    k_bstart_g<<<dim3(1), dim3(1024), 0, stream>>>(btotalA, bucketStartA, NBUCK_M);
    k_bstart_g<<<dim3(1), dim3(1024), 0, stream>>>(btotalS, bucketStartS, NBUCK_M);
    k_bstart_g<<<dim3(1), dim3(1024), 0, stream>>>(btotalR, bucketStartR, NBUCK_R);
    k_rxn_scatter<<<dim3(NBR), blk, 0, stream>>>(
        rxn_sub, met_sub, sto_sub, blockHistR, bucketStartR, recsR);
    k_csr_bucket<<<dim3(NBUCK_R), blk, 0, stream>>>(
        recsR, bucketStartR, cntG, offG, recsC);
    k_msg2<<<dim3((ESUB + 255) / 256), blk, 0, stream>>>(
        recsC, x, sub_w1, sub_b1, sub_w2, msgA, msgB, extS);
    k_rxn3<<<dim3((NRXN + 255) / 256), blk, 0, stream>>>(
        cntG, offG, msgA, msgB, extS, sub_b2,
        rate_w1, rate_b1, rate_w2, rate_b2, log_k, v);
    k_cons_scatter<<<dim3(NBM), blk512, 0, stream>>>(
        met_sub, rxn_sub, sto_sub, v, blockHistS, bucketStartS, recsS);
    k_baccum_tot<<<dim3(NBUCK_M), blk512, 0, stream>>>(
        recsS, bucketStartS, x, met_scale);
    k_rscale<<<dim3((NRXN + 255) / 256), blk, 0, stream>>>(
        cntG, offG, recsC, met_scale, v);
    k_bscatter<<<dim3(NBM), blk512, 0, stream>>>(
        met_all, rxn_all, sto_all, v, blockHistA, bucketStartA, recsA);
    k_baccum<<<dim3(NBUCK_M), blk512, 0, stream>>>(recsA, bucketStartA, x, out);
}

// Round 11
// 181.675 us; speedup vs baseline: 1.3010x; 1.0491x over previous
//
#include <hip/hip_runtime.h>

#define NMET 200000
#define NRXN 400000
#define ESUB 800000
#define EALL 1600000

// met-bucket sort (consume + contrib): bucket = met >> 9, 512 mets/bucket
#define NBUCK_M 391                  // ceil(200000/512)
#define NBM 391                      // blocks for met counting/scatter
#define EBA 4096                     // met_all edges per block (391*4096 >= EALL)
#define EBS 2048                     // met_sub edges per block (391*2048 >= ESUB)

// rxn-bucket sort (CSR build): bucket = rxn >> 9, 512 rxns/bucket
#define NBUCK_R 782                  // ceil(400000/512); 782*512 = 400384
#define NBR 1024                     // blocks for rxn counting/scatter
#define EBR 782                      // edges per block (1024*782 >= ESUB)
#define MET_MASK 0x3FFFF             // 18 bits (NMET < 262144)

// c_target = 1 + 0.5*sin(2*pi*100/1000) = 1.2938926261462366
#define C_TARGET 1.29389262614623664f
#define DT_C 0.01f
#define HOMEO_C 0.1f
#define LOG2_10 3.32192809488736235f

__device__ __forceinline__ float fast_tanh(float x) {
    float e = __expf(2.0f * x);
    return 1.0f - 2.0f * __builtin_amdgcn_rcpf(e + 1.0f);
}

// ---- 1a. met-bucket counts for contrib (A) and consume (S) -----------------
__global__ __launch_bounds__(512) void k_count_met(
    const int* __restrict__ met_all, const int* __restrict__ met_sub,
    int* __restrict__ blockHistA, int* __restrict__ blockHistS)
{
    __shared__ int hA[NBUCK_M];
    __shared__ int hS[NBUCK_M];
    int t = threadIdx.x;
    for (int b = t; b < NBUCK_M; b += 512) { hA[b] = 0; hS[b] = 0; }
    __syncthreads();
    int baseA = blockIdx.x * EBA;
    for (int i = t; i < EBA; i += 512) {
        int e = baseA + i;
        if (e < EALL) atomicAdd(&hA[met_all[e] >> 9], 1);
    }
    int baseS = blockIdx.x * EBS;
    for (int i = t; i < EBS; i += 512) {
        int e = baseS + i;
        if (e < ESUB) atomicAdd(&hS[met_sub[e] >> 9], 1);
    }
    __syncthreads();
    for (int b = t; b < NBUCK_M; b += 512) {
        blockHistA[(size_t)b * NBM + blockIdx.x] = hA[b];
        blockHistS[(size_t)b * NBM + blockIdx.x] = hS[b];
    }
}

// ---- 1b. rxn-bucket counts --------------------------------------------------
__global__ __launch_bounds__(256) void k_count_rxn(
    const int* __restrict__ rxn_sub, int* __restrict__ blockHistR)
{
    __shared__ int hR[NBUCK_R];
    int t = threadIdx.x;
    for (int b = t; b < NBUCK_R; b += 256) hR[b] = 0;
    __syncthreads();
    int base = blockIdx.x * EBR;
    for (int i = t; i < EBR; i += 256) {
        int e = base + i;
        if (e < ESUB) atomicAdd(&hR[rxn_sub[e] >> 9], 1);
    }
    __syncthreads();
    for (int b = t; b < NBUCK_R; b += 256)
        blockHistR[(size_t)b * NBR + blockIdx.x] = hR[b];
}

// ---- 2. generic per-bucket scan over nb block counts (in place) ------------
__global__ __launch_bounds__(256) void k_bscan_g(
    int* __restrict__ hist, int* __restrict__ total, int nb)
{
    __shared__ int lds[256];
    __shared__ int carry_s;
    int t = threadIdx.x;
    size_t base = (size_t)blockIdx.x * nb;
    if (t == 0) carry_s = 0;
    __syncthreads();
    for (int off0 = 0; off0 < nb; off0 += 256) {
        int i = off0 + t;
        int val = (i < nb) ? hist[base + i] : 0;
        lds[t] = val;
        __syncthreads();
        for (int off = 1; off < 256; off <<= 1) {
            int add = (t >= off) ? lds[t - off] : 0;
            __syncthreads();
            lds[t] += add;
            __syncthreads();
        }
        int incl = lds[t];
        int carry = carry_s;
        if (i < nb) hist[base + i] = carry + incl - val;
        __syncthreads();
        if (t == 255) carry_s = carry + incl;
        __syncthreads();
    }
    if (t == 0) total[blockIdx.x] = carry_s;
}

// ---- 3. generic one-block scan of bucket totals -> bucketStart -------------
__global__ __launch_bounds__(1024) void k_bstart_g(
    const int* __restrict__ total, int* __restrict__ start, int nbuck)
{
    __shared__ int lds[1024];
    int t = threadIdx.x;
    int val = (t < nbuck) ? total[t] : 0;
    lds[t] = val;
    __syncthreads();
    for (int off = 1; off < 1024; off <<= 1) {
        int add = (t >= off) ? lds[t - off] : 0;
        __syncthreads();
        lds[t] += add;
        __syncthreads();
    }
    if (t < nbuck) start[t] = lds[t] - val;
    if (t == 1023) start[nbuck] = lds[1023];
}

// ---- 4. scatter rxn records {met | rloc<<18, sto} into rxn buckets ---------
__global__ __launch_bounds__(256) void k_rxn_scatter(
    const int* __restrict__ rxn_sub, const int* __restrict__ met_sub,
    const float* __restrict__ sto_sub,
    const int* __restrict__ blockHistR, const int* __restrict__ bucketStartR,
    uint2* __restrict__ recsR)
{
    __shared__ int bbase[NBUCK_R];
    __shared__ int h[NBUCK_R];
    int t = threadIdx.x;
    for (int b = t; b < NBUCK_R; b += 256) {
        h[b] = 0;
        bbase[b] = bucketStartR[b] + blockHistR[(size_t)b * NBR + blockIdx.x];
    }
    __syncthreads();
    int base = blockIdx.x * EBR;
    for (int i = t; i < EBR; i += 256) {
        int e = base + i;
        if (e < ESUB) {
            int r = rxn_sub[e];
            int b = r >> 9;
            int rloc = r & 511;
            int slot = bbase[b] + atomicAdd(&h[b], 1);
            uint2 rec;
            rec.x = (unsigned)(met_sub[e] | (rloc << 18));
            rec.y = __float_as_uint(sto_sub[e]);
            recsR[slot] = rec;
        }
    }
}

// ---- 5. per-bucket CSR finalize: count rlocs, local scan, reorder ----------
__global__ __launch_bounds__(256) void k_csr_bucket(
    const uint2* __restrict__ recsR, const int* __restrict__ bucketStartR,
    int* __restrict__ cntG, int* __restrict__ offG, uint2* __restrict__ recsC)
{
    __shared__ int cnt[512];
    __shared__ int loff[512];
    __shared__ int pscan[256];
    __shared__ int rnk[512];
    int t = threadIdx.x;
    cnt[t] = 0; cnt[t + 256] = 0;
    rnk[t] = 0; rnk[t + 256] = 0;
    __syncthreads();

    int b = blockIdx.x;
    int s = bucketStartR[b], epos = bucketStartR[b + 1];
    for (int i = s + t; i < epos; i += 256)
        atomicAdd(&cnt[(recsR[i].x >> 18) & 511], 1);
    __syncthreads();

    int c0 = cnt[2 * t], c1 = cnt[2 * t + 1];
    int ps = c0 + c1;
    pscan[t] = ps;
    __syncthreads();
    for (int off = 1; off < 256; off <<= 1) {
        int add = (t >= off) ? pscan[t - off] : 0;
        __syncthreads();
        pscan[t] += add;
        __syncthreads();
    }
    int excl = pscan[t] - ps;
    loff[2 * t] = excl;
    loff[2 * t + 1] = excl + c0;
    __syncthreads();

    int gb = b << 9;
    for (int j = t; j < 512; j += 256) {
        cntG[gb + j] = cnt[j];
        offG[gb + j] = s + loff[j];
    }

    for (int i = s + t; i < epos; i += 256) {
        uint2 rec = recsR[i];
        int rloc = (rec.x >> 18) & 511;
        int pos = loff[rloc] + atomicAdd(&rnk[rloc], 1);
        recsC[s + pos] = rec;
    }
}

// ---- 6. slot-parallel edge MLP over CSR-ordered records --------------------
__global__ __launch_bounds__(256) void k_msg2(
    const uint2* __restrict__ recsC, const float* __restrict__ x,
    const float* __restrict__ sub_w1, const float* __restrict__ sub_b1,
    const float* __restrict__ sub_w2,
    float4* __restrict__ msgA, float4* __restrict__ msgB,
    float* __restrict__ extS)
{
    __shared__ float sW1[128];
    __shared__ float sB1[64];
    __shared__ __align__(16) float sW2[512];
    int t = threadIdx.x;
    for (int i = t; i < 128; i += 256) sW1[i] = sub_w1[i];
    for (int i = t; i < 64;  i += 256) sB1[i] = sub_b1[i];
    for (int i = t; i < 512; i += 256) sW2[i] = sub_w2[i];
    __syncthreads();

    int i = blockIdx.x * 256 + t;
    if (i >= ESUB) return;
    uint2 rec = recsC[i];
    int m = rec.x & MET_MASK;
    float st = __uint_as_float(rec.y);
    float c  = x[(size_t)m * 8 + 3];
    float ex = x[(size_t)m * 8 + 4];

    float m0 = 0.f, m1 = 0.f, m2 = 0.f, m3 = 0.f;
    float m4 = 0.f, m5 = 0.f, m6 = 0.f, m7 = 0.f;
    #pragma unroll 8
    for (int j = 0; j < 64; ++j) {
        float z = fmaf(c, sW1[j], fmaf(st, sW1[64 + j], sB1[j]));
        float th = fast_tanh(z);
        float4 wa = *(const float4*)&sW2[j * 8];
        float4 wb = *(const float4*)&sW2[j * 8 + 4];
        m0 = fmaf(th, wa.x, m0); m1 = fmaf(th, wa.y, m1);
        m2 = fmaf(th, wa.z, m2); m3 = fmaf(th, wa.w, m3);
        m4 = fmaf(th, wb.x, m4); m5 = fmaf(th, wb.y, m5);
        m6 = fmaf(th, wb.z, m6); m7 = fmaf(th, wb.w, m7);
    }
    msgA[i] = make_float4(m0, m1, m2, m3);
    msgB[i] = make_float4(m4, m5, m6, m7);
    extS[i] = ex;
}

// ---- 7. per-reaction: contiguous msg segment sum, rate MLP -> v ------------
__global__ __launch_bounds__(256) void k_rxn3(
    const int* __restrict__ cntG, const int* __restrict__ offG,
    const float4* __restrict__ msgA, const float4* __restrict__ msgB,
    const float* __restrict__ extS,
    const float* __restrict__ sub_b2,
    const float* __restrict__ rate_w1, const float* __restrict__ rate_b1,
    const float* __restrict__ rate_w2, const float* __restrict__ rate_b2,
    const float* __restrict__ log_k, float* __restrict__ v)
{
    __shared__ __align__(16) float sR1[512];
    __shared__ float sRB1[64];
    __shared__ float sR2[64];
    __shared__ float sB2[8];
    __shared__ float sRB2;
    int t = threadIdx.x;
    for (int i = t; i < 512; i += 256) sR1[i] = rate_w1[i];
    if (t < 64) { sRB1[t] = rate_b1[t]; sR2[t] = rate_w2[t]; }
    if (t < 8) sB2[t] = sub_b2[t];
    if (t == 64) sRB2 = rate_b2[0];
    __syncthreads();

    int r = blockIdx.x * 256 + t;
    if (r >= NRXN) return;
    int n = cntG[r];
    int base = offG[r];
    float fn = (float)n;

    float h0 = fn * sB2[0], h1 = fn * sB2[1], h2 = fn * sB2[2], h3 = fn * sB2[3];
    float h4 = fn * sB2[4], h5 = fn * sB2[5], h6 = fn * sB2[6], h7 = fn * sB2[7];
    float exs = 0.f;
    for (int i = 0; i < n; ++i) {
        float4 a = msgA[base + i];
        float4 b = msgB[base + i];
        h0 += a.x; h1 += a.y; h2 += a.z; h3 += a.w;
        h4 += b.x; h5 += b.y; h6 += b.z; h7 += b.w;
        exs += extS[base + i];
    }

    float acc = sRB2;
    #pragma unroll 4
    for (int j = 0; j < 64; ++j) {
        float z = sRB1[j];
        z = fmaf(h0, sR1[j],       z);
        z = fmaf(h1, sR1[64 + j],  z);
        z = fmaf(h2, sR1[128 + j], z);
        z = fmaf(h3, sR1[192 + j], z);
        z = fmaf(h4, sR1[256 + j], z);
        z = fmaf(h5, sR1[320 + j], z);
        z = fmaf(h6, sR1[384 + j], z);
        z = fmaf(h7, sR1[448 + j], z);
        acc = fmaf(fast_tanh(z), sR2[j], acc);
    }
    float nmax = fmaxf(fn, 1.0f);
    float ext_mean = 2.0f * exs * __builtin_amdgcn_rcpf(nmax);
    float kk = exp2f(log_k[r] * LOG2_10);
    v[r] = kk * ext_mean * acc;
}

// ---- 8. consume bucket-scatter with LDS-staged counting sort ---------------
__global__ __launch_bounds__(512) void k_cons_scatter(
    const int* __restrict__ met_sub, const int* __restrict__ rxn_sub,
    const float* __restrict__ sto_sub, const float* __restrict__ v,
    const int* __restrict__ blockHistS, const int* __restrict__ bucketStartS,
    uint2* __restrict__ recsS)
{
    __shared__ int cnt[NBUCK_M];
    __shared__ int loff[NBUCK_M];
    __shared__ int rnk[NBUCK_M];
    __shared__ int bbase[NBUCK_M];
    __shared__ int sc[512];
    __shared__ uint2 stage[EBS];
    int t = threadIdx.x;
    for (int b = t; b < NBUCK_M; b += 512) {
        cnt[b] = 0; rnk[b] = 0;
        bbase[b] = bucketStartS[b] + blockHistS[(size_t)b * NBM + blockIdx.x];
    }
    __syncthreads();
    int base = blockIdx.x * EBS;
    int nrec = ESUB - base; if (nrec > EBS) nrec = EBS; if (nrec < 0) nrec = 0;

    // pass 1: local histogram
    for (int i = t; i < nrec; i += 512)
        atomicAdd(&cnt[met_sub[base + i] >> 9], 1);
    __syncthreads();
    // local exclusive scan over buckets
    int cval = (t < NBUCK_M) ? cnt[t] : 0;
    sc[t] = cval;
    __syncthreads();
    for (int off = 1; off < 512; off <<= 1) {
        int add = (t >= off) ? sc[t - off] : 0;
        __syncthreads();
        sc[t] += add;
        __syncthreads();
    }
    if (t < NBUCK_M) loff[t] = sc[t] - cval;
    __syncthreads();
    // pass 2: place records into LDS, sorted by bucket
    for (int i = t; i < nrec; i += 512) {
        int e = base + i;
        int m = met_sub[e];
        int b = m >> 9;
        float val = sto_sub[e] * v[rxn_sub[e]] * DT_C;
        int pos = loff[b] + atomicAdd(&rnk[b], 1);
        uint2 rec;
        rec.x = (unsigned)m;
        rec.y = __float_as_uint(val);
        stage[pos] = rec;
    }
    __syncthreads();
    // pass 3: drain LDS linearly -> coalesced run writes
    for (int j = t; j < nrec; j += 512) {
        uint2 rec = stage[j];
        int b = (int)(rec.x >> 9);
        recsS[bbase[b] + (j - loff[b])] = rec;
    }
}

// ---- 9. per-bucket accumulate total -> met_scale ---------------------------
__global__ __launch_bounds__(512) void k_baccum_tot(
    const uint2* __restrict__ recsS, const int* __restrict__ bucketStartS,
    const float* __restrict__ x, float* __restrict__ met_scale)
{
    __shared__ float acc[512];
    int b = blockIdx.x;
    int t = threadIdx.x;
    acc[t] = 0.f;
    __syncthreads();
    int s = bucketStartS[b], epos = bucketStartS[b + 1];
    for (int i = s + t; i < epos; i += 512) {
        uint2 rec = recsS[i];
        atomicAdd(&acc[rec.x & 511], __uint_as_float(rec.y));
    }
    __syncthreads();
    int m = (b << 9) + t;
    if (m < NMET) {
        float tot = acc[t];
        float ms = 1.0f;
        if (tot > 1e-12f) ms = fminf(x[(size_t)m * 8 + 3] / tot, 1.0f);
        met_scale[m] = ms;
    }
}

// ---- 10. per-reaction min over CSR records + v scale -----------------------
__global__ __launch_bounds__(256) void k_rscale(
    const int* __restrict__ cntG, const int* __restrict__ offG,
    const uint2* __restrict__ recsC, const float* __restrict__ met_scale,
    float* __restrict__ v)
{
    int r = blockIdx.x * 256 + threadIdx.x;
    if (r >= NRXN) return;
    int n = cntG[r];
    int base = offG[r];
    float ms = 1.0f;
    for (int i = 0; i < n; ++i)
        ms = fminf(ms, met_scale[recsC[base + i].x & MET_MASK]);
    v[r] *= ms;
}

// ---- 11. contrib bucket-scatter with LDS-staged counting sort --------------
__global__ __launch_bounds__(512) void k_bscatter(
    const int* __restrict__ met_all, const int* __restrict__ rxn_all,
    const float* __restrict__ sto_all, const float* __restrict__ v,
    const int* __restrict__ blockHistA, const int* __restrict__ bucketStartA,
    uint2* __restrict__ recsA)
{
    __shared__ int cnt[NBUCK_M];
    __shared__ int loff[NBUCK_M];
    __shared__ int rnk[NBUCK_M];
    __shared__ int bbase[NBUCK_M];
    __shared__ int sc[512];
    __shared__ uint2 stage[EBA];
    int t = threadIdx.x;
    for (int b = t; b < NBUCK_M; b += 512) {
        cnt[b] = 0; rnk[b] = 0;
        bbase[b] = bucketStartA[b] + blockHistA[(size_t)b * NBM + blockIdx.x];
    }
    __syncthreads();
    int base = blockIdx.x * EBA;
    int nrec = EALL - base; if (nrec > EBA) nrec = EBA; if (nrec < 0) nrec = 0;

    // pass 1: local histogram
    for (int i = t; i < nrec; i += 512)
        atomicAdd(&cnt[met_all[base + i] >> 9], 1);
    __syncthreads();
    // local exclusive scan
    int cval = (t < NBUCK_M) ? cnt[t] : 0;
    sc[t] = cval;
    __syncthreads();
    for (int off = 1; off < 512; off <<= 1) {
        int add = (t >= off) ? sc[t - off] : 0;
        __syncthreads();
        sc[t] += add;
        __syncthreads();
    }
    if (t < NBUCK_M) loff[t] = sc[t] - cval;
    __syncthreads();
    // pass 2: place into LDS sorted by bucket
    for (int i = t; i < nrec; i += 512) {
        int e = base + i;
        int m = met_all[e];
        int b = m >> 9;
        float val = sto_all[e] * v[rxn_all[e]];
        int pos = loff[b] + atomicAdd(&rnk[b], 1);
        uint2 rec;
        rec.x = (unsigned)m;
        rec.y = __float_as_uint(val);
        stage[pos] = rec;
    }
    __syncthreads();
    // pass 3: drain LDS linearly -> coalesced run writes
    for (int j = t; j < nrec; j += 512) {
        uint2 rec = stage[j];
        int b = (int)(rec.x >> 9);
        recsA[bbase[b] + (j - loff[b])] = rec;
    }
}

// ---- 12. per-bucket accumulate + homeostasis epilogue ----------------------
__global__ __launch_bounds__(512) void k_baccum(
    const uint2* __restrict__ recsA, const int* __restrict__ bucketStartA,
    const float* __restrict__ x, float* __restrict__ out)
{
    __shared__ float acc[512];
    int b = blockIdx.x;
    int t = threadIdx.x;
    acc[t] = 0.f;
    __syncthreads();
    int s = bucketStartA[b], epos = bucketStartA[b + 1];
    for (int i = s + t; i < epos; i += 512) {
        uint2 rec = recsA[i];
        atomicAdd(&acc[rec.x & 511], __uint_as_float(rec.y));
    }
    __syncthreads();
    int m = (b << 9) + t;
    if (m < NMET) {
        float c = x[(size_t)m * 8 + 3];
        out[m] = acc[t] - HOMEO_C * (c - C_TARGET);
    }
}

extern "C" void kernel_launch(void* const* d_in, const int* in_sizes, int n_in,
                              void* d_out, int out_size, void* d_ws, size_t ws_size,
                              hipStream_t stream) {
    const float* x       = (const float*)d_in[0];
    const int*   met_sub = (const int*)  d_in[1];
    const int*   rxn_sub = (const int*)  d_in[2];
    const float* sto_sub = (const float*)d_in[3];
    const int*   met_all = (const int*)  d_in[4];
    const int*   rxn_all = (const int*)  d_in[5];
    const float* sto_all = (const float*)d_in[6];
    const float* sub_w1  = (const float*)d_in[7];
    const float* sub_b1  = (const float*)d_in[8];
    const float* sub_w2  = (const float*)d_in[9];
    const float* sub_b2  = (const float*)d_in[10];
    const float* rate_w1 = (const float*)d_in[11];
    const float* rate_b1 = (const float*)d_in[12];
    const float* rate_w2 = (const float*)d_in[13];
    const float* rate_b2 = (const float*)d_in[14];
    const float* log_k   = (const float*)d_in[15];

    char* ws = (char*)d_ws;
    float4* msgA  = (float4*)ws;                                // ESUB
    float4* msgB  = msgA + ESUB;                                // ESUB
    uint2*  recsR = (uint2*)(msgB + ESUB);                      // ESUB
    uint2*  recsC = recsR + ESUB;                               // ESUB
    uint2*  recsS = recsC + ESUB;                               // ESUB
    uint2*  recsA = recsS + ESUB;                               // EALL
    float*  extS  = (float*)(recsA + EALL);                     // ESUB
    float*  v     = extS + ESUB;                                // NRXN
    float*  met_scale = v + NRXN;                               // NMET
    int* cntG = (int*)(met_scale + NMET);                       // NBUCK_R*512
    int* offG = cntG + (size_t)NBUCK_R * 512;                   // NBUCK_R*512
    int* blockHistA = offG + (size_t)NBUCK_R * 512;             // NBUCK_M*NBM
    int* blockHistS = blockHistA + (size_t)NBUCK_M * NBM;       // NBUCK_M*NBM
    int* blockHistR = blockHistS + (size_t)NBUCK_M * NBM;       // NBUCK_R*NBR
    int* btotalA = blockHistR + (size_t)NBUCK_R * NBR;          // NBUCK_M
    int* bucketStartA = btotalA + NBUCK_M;                      // NBUCK_M+1
    int* btotalS = bucketStartA + NBUCK_M + 1;                  // NBUCK_M
    int* bucketStartS = btotalS + NBUCK_M;                      // NBUCK_M+1
    int* btotalR = bucketStartS + NBUCK_M + 1;                  // NBUCK_R
    int* bucketStartR = btotalR + NBUCK_R;                      // NBUCK_R+1
    float* out = (float*)d_out;

    dim3 blk(256);
    dim3 blk512(512);
    k_count_met<<<dim3(NBM), blk512, 0, stream>>>(met_all, met_sub, blockHistA, blockHistS);
    k_count_rxn<<<dim3(NBR), blk, 0, stream>>>(rxn_sub, blockHistR);
    k_bscan_g<<<dim3(NBUCK_M), blk, 0, stream>>>(blockHistA, btotalA, NBM);
    k_bscan_g<<<dim3(NBUCK_M), blk, 0, stream>>>(blockHistS, btotalS, NBM);
    k_bscan_g<<<dim3(NBUCK_R), blk, 0, stream>>>(blockHistR, btotalR, NBR);
    k_bstart_g<<<dim3(1), dim3(1024), 0, stream>>>(btotalA, bucketStartA, NBUCK_M);
    k_bstart_g<<<dim3(1), dim3(1024), 0, stream>>>(btotalS, bucketStartS, NBUCK_M);
    k_bstart_g<<<dim3(1), dim3(1024), 0, stream>>>(btotalR, bucketStartR, NBUCK_R);
    k_rxn_scatter<<<dim3(NBR), blk, 0, stream>>>(
        rxn_sub, met_sub, sto_sub, blockHistR, bucketStartR, recsR);
    k_csr_bucket<<<dim3(NBUCK_R), blk, 0, stream>>>(
        recsR, bucketStartR, cntG, offG, recsC);
    k_msg2<<<dim3((ESUB + 255) / 256), blk, 0, stream>>>(
        recsC, x, sub_w1, sub_b1, sub_w2, msgA, msgB, extS);
    k_rxn3<<<dim3((NRXN + 255) / 256), blk, 0, stream>>>(
        cntG, offG, msgA, msgB, extS, sub_b2,
        rate_w1, rate_b1, rate_w2, rate_b2, log_k, v);
    k_cons_scatter<<<dim3(NBM), blk512, 0, stream>>>(
        met_sub, rxn_sub, sto_sub, v, blockHistS, bucketStartS, recsS);
    k_baccum_tot<<<dim3(NBUCK_M), blk512, 0, stream>>>(
        recsS, bucketStartS, x, met_scale);
    k_rscale<<<dim3((NRXN + 255) / 256), blk, 0, stream>>>(
        cntG, offG, recsC, met_scale, v);
    k_bscatter<<<dim3(NBM), blk512, 0, stream>>>(
        met_all, rxn_all, sto_all, v, blockHistA, bucketStartA, recsA);
    k_baccum<<<dim3(NBUCK_M), blk512, 0, stream>>>(recsA, bucketStartA, x, out);
}

// Round 12
// 162.261 us; speedup vs baseline: 1.4567x; 1.1196x over previous
//
#include <hip/hip_runtime.h>

#define NMET 200000
#define NRXN 400000
#define ESUB 800000
#define EALL 1600000

// unified streaming decomposition: 196 blocks for all count/scatter kernels
#define NBB 196
#define EBA 8192                     // met_all per block  (196*8192 >= EALL)
#define EBS 4096                     // met_sub / rxn_sub per block (196*4096 >= ESUB)

#define NBUCK_M 391                  // met buckets  (met >> 9)
#define NBUCK_R 782                  // rxn buckets  (rxn >> 9)
#define MET_MASK 0x3FFFF             // 18 bits
#define MCAP 1280                    // LDS msg tile capacity (mean bucket = 1024 recs)

// c_target = 1 + 0.5*sin(2*pi*100/1000)
#define C_TARGET 1.29389262614623664f
#define DT_C 0.01f
#define HOMEO_C 0.1f
#define LOG2_10 3.32192809488736235f

__device__ __forceinline__ float fast_tanh(float x) {
    float e = __expf(2.0f * x);
    return 1.0f - 2.0f * __builtin_amdgcn_rcpf(e + 1.0f);
}

// ---- 1. all three bucket histograms in one pass ----------------------------
__global__ __launch_bounds__(512) void k_count_all(
    const int* __restrict__ met_all, const int* __restrict__ met_sub,
    const int* __restrict__ rxn_sub,
    int* __restrict__ blockHistA, int* __restrict__ blockHistS,
    int* __restrict__ blockHistR)
{
    __shared__ int hA[NBUCK_M];
    __shared__ int hS[NBUCK_M];
    __shared__ int hR[NBUCK_R];
    int t = threadIdx.x;
    for (int b = t; b < NBUCK_R; b += 512) hR[b] = 0;
    for (int b = t; b < NBUCK_M; b += 512) { hA[b] = 0; hS[b] = 0; }
    __syncthreads();
    int baseA = blockIdx.x * EBA;
    for (int i = t; i < EBA; i += 512) {
        int e = baseA + i;
        if (e < EALL) atomicAdd(&hA[met_all[e] >> 9], 1);
    }
    int baseS = blockIdx.x * EBS;
    for (int i = t; i < EBS; i += 512) {
        int e = baseS + i;
        if (e < ESUB) {
            atomicAdd(&hS[met_sub[e] >> 9], 1);
            atomicAdd(&hR[rxn_sub[e] >> 9], 1);
        }
    }
    __syncthreads();
    for (int b = t; b < NBUCK_M; b += 512) {
        blockHistA[(size_t)b * NBB + blockIdx.x] = hA[b];
        blockHistS[(size_t)b * NBB + blockIdx.x] = hS[b];
    }
    for (int b = t; b < NBUCK_R; b += 512)
        blockHistR[(size_t)b * NBB + blockIdx.x] = hR[b];
}

// ---- 2. all per-bucket scans over the NBB block counts in one dispatch -----
__global__ __launch_bounds__(256) void k_scan_all(
    int* __restrict__ blockHistA, int* __restrict__ blockHistS,
    int* __restrict__ blockHistR,
    int* __restrict__ btotalA, int* __restrict__ btotalS,
    int* __restrict__ btotalR)
{
    __shared__ int sc[256];
    int bid = blockIdx.x;
    int* row; int* tot;
    if (bid < NBUCK_M) { row = blockHistA + (size_t)bid * NBB; tot = btotalA + bid; }
    else if (bid < 2 * NBUCK_M) { row = blockHistS + (size_t)(bid - NBUCK_M) * NBB; tot = btotalS + (bid - NBUCK_M); }
    else { row = blockHistR + (size_t)(bid - 2 * NBUCK_M) * NBB; tot = btotalR + (bid - 2 * NBUCK_M); }
    int t = threadIdx.x;
    int val = (t < NBB) ? row[t] : 0;
    sc[t] = val;
    __syncthreads();
    for (int off = 1; off < 256; off <<= 1) {
        int add = (t >= off) ? sc[t - off] : 0;
        __syncthreads();
        sc[t] += add;
        __syncthreads();
    }
    if (t < NBB) row[t] = sc[t] - val;
    if (t == 255) *tot = sc[255];
}

// ---- 3. three bucket-total scans in one dispatch ---------------------------
__global__ __launch_bounds__(1024) void k_bstart3(
    const int* __restrict__ btotalA, int* __restrict__ startA,
    const int* __restrict__ btotalS, int* __restrict__ startS,
    const int* __restrict__ btotalR, int* __restrict__ startR)
{
    __shared__ int lds[1024];
    const int* tot; int* st; int nb;
    if (blockIdx.x == 0)      { tot = btotalA; st = startA; nb = NBUCK_M; }
    else if (blockIdx.x == 1) { tot = btotalS; st = startS; nb = NBUCK_M; }
    else                      { tot = btotalR; st = startR; nb = NBUCK_R; }
    int t = threadIdx.x;
    int val = (t < nb) ? tot[t] : 0;
    lds[t] = val;
    __syncthreads();
    for (int off = 1; off < 1024; off <<= 1) {
        int add = (t >= off) ? lds[t - off] : 0;
        __syncthreads();
        lds[t] += add;
        __syncthreads();
    }
    if (t < nb) st[t] = lds[t] - val;
    if (t == 1023) st[nb] = lds[1023];
}

// ---- 4. rxn-record scatter with LDS counting-sort staging ------------------
__global__ __launch_bounds__(512) void k_rxn_scatter(
    const int* __restrict__ rxn_sub, const int* __restrict__ met_sub,
    const float* __restrict__ sto_sub,
    const int* __restrict__ blockHistR, const int* __restrict__ bucketStartR,
    uint2* __restrict__ recsR)
{
    __shared__ int cnt[NBUCK_R];
    __shared__ int loff[NBUCK_R];
    __shared__ int rnk[NBUCK_R];
    __shared__ int bbase[NBUCK_R];
    __shared__ unsigned short sbuck[EBS];
    __shared__ uint2 stage[EBS];
    __shared__ int sc[512];
    __shared__ int carry_s;
    int t = threadIdx.x;
    for (int b = t; b < NBUCK_R; b += 512) {
        cnt[b] = 0; rnk[b] = 0;
        bbase[b] = bucketStartR[b] + blockHistR[(size_t)b * NBB + blockIdx.x];
    }
    if (t == 0) carry_s = 0;
    __syncthreads();
    int base = blockIdx.x * EBS;
    int nrec = ESUB - base; if (nrec > EBS) nrec = EBS; if (nrec < 0) nrec = 0;

    for (int i = t; i < nrec; i += 512)
        atomicAdd(&cnt[rxn_sub[base + i] >> 9], 1);
    __syncthreads();
    // 782-wide exclusive scan with 512 threads (2 passes + carry)
    for (int b0 = 0; b0 < NBUCK_R; b0 += 512) {
        int idx = b0 + t;
        int val = (idx < NBUCK_R) ? cnt[idx] : 0;
        sc[t] = val;
        __syncthreads();
        for (int off = 1; off < 512; off <<= 1) {
            int add = (t >= off) ? sc[t - off] : 0;
            __syncthreads();
            sc[t] += add;
            __syncthreads();
        }
        if (idx < NBUCK_R) loff[idx] = carry_s + sc[t] - val;
        __syncthreads();
        if (t == 511) carry_s += sc[511];
        __syncthreads();
    }
    for (int i = t; i < nrec; i += 512) {
        int e = base + i;
        int r = rxn_sub[e];
        int b = r >> 9;
        int pos = loff[b] + atomicAdd(&rnk[b], 1);
        uint2 rec;
        rec.x = (unsigned)(met_sub[e] | ((r & 511) << 18));
        rec.y = __float_as_uint(sto_sub[e]);
        stage[pos] = rec;
        sbuck[pos] = (unsigned short)b;
    }
    __syncthreads();
    for (int j = t; j < nrec; j += 512) {
        int b = sbuck[j];
        recsR[bbase[b] + (j - loff[b])] = stage[j];
    }
}

// ---- 5. per-bucket CSR finalize: count rlocs, local scan, reorder ----------
__global__ __launch_bounds__(256) void k_csr_bucket(
    const uint2* __restrict__ recsR, const int* __restrict__ bucketStartR,
    int* __restrict__ cntG, int* __restrict__ offG, uint2* __restrict__ recsC)
{
    __shared__ int cnt[512];
    __shared__ int loff[512];
    __shared__ int pscan[256];
    __shared__ int rnk[512];
    int t = threadIdx.x;
    cnt[t] = 0; cnt[t + 256] = 0;
    rnk[t] = 0; rnk[t + 256] = 0;
    __syncthreads();

    int b = blockIdx.x;
    int s = bucketStartR[b], epos = bucketStartR[b + 1];
    for (int i = s + t; i < epos; i += 256)
        atomicAdd(&cnt[(recsR[i].x >> 18) & 511], 1);
    __syncthreads();

    int c0 = cnt[2 * t], c1 = cnt[2 * t + 1];
    int ps = c0 + c1;
    pscan[t] = ps;
    __syncthreads();
    for (int off = 1; off < 256; off <<= 1) {
        int add = (t >= off) ? pscan[t - off] : 0;
        __syncthreads();
        pscan[t] += add;
        __syncthreads();
    }
    int excl = pscan[t] - ps;
    loff[2 * t] = excl;
    loff[2 * t + 1] = excl + c0;
    __syncthreads();

    int gb = b << 9;
    for (int j = t; j < 512; j += 256) {
        cntG[gb + j] = cnt[j];
        offG[gb + j] = s + loff[j];
    }

    for (int i = s + t; i < epos; i += 256) {
        uint2 rec = recsR[i];
        int rloc = (rec.x >> 18) & 511;
        int pos = loff[rloc] + atomicAdd(&rnk[rloc], 1);
        recsC[s + pos] = rec;
    }
}

// ---- 6. FUSED per-bucket: edge MLP -> LDS msg tile -> segment sum -> rate MLP
__global__ __launch_bounds__(512) void k_bucket2(
    const uint2* __restrict__ recsC, const int* __restrict__ bucketStartR,
    const int* __restrict__ cntG, const int* __restrict__ offG,
    const float* __restrict__ x,
    const float* __restrict__ sub_w1, const float* __restrict__ sub_b1,
    const float* __restrict__ sub_w2, const float* __restrict__ sub_b2,
    const float* __restrict__ rate_w1, const float* __restrict__ rate_b1,
    const float* __restrict__ rate_w2, const float* __restrict__ rate_b2,
    const float* __restrict__ log_k, float* __restrict__ v)
{
    __shared__ float sW1[128];
    __shared__ float sB1[64];
    __shared__ __align__(16) float sW2[512];
    __shared__ __align__(16) float sR1[512];
    __shared__ float sRB1[64];
    __shared__ float sR2[64];
    __shared__ float sB2[8];
    __shared__ float sRB2;
    __shared__ float msgL[MCAP][9];     // 8 msg + ext per record; 46 KB
    int t = threadIdx.x;
    sW2[t] = sub_w2[t];
    sR1[t] = rate_w1[t];
    if (t < 128) sW1[t] = sub_w1[t];
    if (t < 64) { sB1[t] = sub_b1[t]; sRB1[t] = rate_b1[t]; sR2[t] = rate_w2[t]; }
    if (t < 8) sB2[t] = sub_b2[t];
    if (t == 8) sRB2 = rate_b2[0];
    __syncthreads();

    int b = blockIdx.x;
    int s = bucketStartR[b], epos = bucketStartR[b + 1];
    int gr = (b << 9) + t;              // this thread's reaction
    int n = cntG[gr];
    int base = offG[gr];                // absolute CSR slot
    float fn = (float)n;
    float h0 = fn * sB2[0], h1 = fn * sB2[1], h2 = fn * sB2[2], h3 = fn * sB2[3];
    float h4 = fn * sB2[4], h5 = fn * sB2[5], h6 = fn * sB2[6], h7 = fn * sB2[7];
    float exs = 0.f;

    for (int cb = s; cb < epos; cb += MCAP) {
        int ce = epos; if (ce > cb + MCAP) ce = cb + MCAP;
        // phase A: edge-parallel MLP into LDS tile (uniform, divergence-free)
        for (int i = cb + t; i < ce; i += 512) {
            uint2 rec = recsC[i];
            int m = rec.x & MET_MASK;
            float st = __uint_as_float(rec.y);
            float c  = x[(size_t)m * 8 + 3];
            float ex = x[(size_t)m * 8 + 4];
            float m0 = 0.f, m1 = 0.f, m2 = 0.f, m3 = 0.f;
            float m4 = 0.f, m5 = 0.f, m6 = 0.f, m7 = 0.f;
            #pragma unroll 8
            for (int j = 0; j < 64; ++j) {
                float z = fmaf(c, sW1[j], fmaf(st, sW1[64 + j], sB1[j]));
                float th = fast_tanh(z);
                float4 wa = *(const float4*)&sW2[j * 8];
                float4 wb = *(const float4*)&sW2[j * 8 + 4];
                m0 = fmaf(th, wa.x, m0); m1 = fmaf(th, wa.y, m1);
                m2 = fmaf(th, wa.z, m2); m3 = fmaf(th, wa.w, m3);
                m4 = fmaf(th, wb.x, m4); m5 = fmaf(th, wb.y, m5);
                m6 = fmaf(th, wb.z, m6); m7 = fmaf(th, wb.w, m7);
            }
            float* row = msgL[i - cb];
            row[0] = m0; row[1] = m1; row[2] = m2; row[3] = m3;
            row[4] = m4; row[5] = m5; row[6] = m6; row[7] = m7;
            row[8] = ex;
        }
        __syncthreads();
        // phase B: per-rxn contiguous segment sum from LDS
        int lo = base;         if (lo < cb) lo = cb;
        int hi = base + n;     if (hi > ce) hi = ce;
        for (int k = lo; k < hi; ++k) {
            float* row = msgL[k - cb];
            h0 += row[0]; h1 += row[1]; h2 += row[2]; h3 += row[3];
            h4 += row[4]; h5 += row[5]; h6 += row[6]; h7 += row[7];
            exs += row[8];
        }
        __syncthreads();
    }

    if (gr < NRXN) {
        float acc = sRB2;
        #pragma unroll 4
        for (int j = 0; j < 64; ++j) {
            float z = sRB1[j];
            z = fmaf(h0, sR1[j],       z);
            z = fmaf(h1, sR1[64 + j],  z);
            z = fmaf(h2, sR1[128 + j], z);
            z = fmaf(h3, sR1[192 + j], z);
            z = fmaf(h4, sR1[256 + j], z);
            z = fmaf(h5, sR1[320 + j], z);
            z = fmaf(h6, sR1[384 + j], z);
            z = fmaf(h7, sR1[448 + j], z);
            acc = fmaf(fast_tanh(z), sR2[j], acc);
        }
        float nmax = fmaxf(fn, 1.0f);
        float ext_mean = 2.0f * exs * __builtin_amdgcn_rcpf(nmax);
        float kk = exp2f(log_k[gr] * LOG2_10);
        v[gr] = kk * ext_mean * acc;
    }
}

// ---- 7. consume bucket-scatter with LDS counting-sort staging --------------
__global__ __launch_bounds__(512) void k_cons_scatter(
    const int* __restrict__ met_sub, const int* __restrict__ rxn_sub,
    const float* __restrict__ sto_sub, const float* __restrict__ v,
    const int* __restrict__ blockHistS, const int* __restrict__ bucketStartS,
    uint2* __restrict__ recsS)
{
    __shared__ int cnt[NBUCK_M];
    __shared__ int loff[NBUCK_M];
    __shared__ int rnk[NBUCK_M];
    __shared__ int bbase[NBUCK_M];
    __shared__ int sc[512];
    __shared__ uint2 stage[EBS];
    int t = threadIdx.x;
    for (int b = t; b < NBUCK_M; b += 512) {
        cnt[b] = 0; rnk[b] = 0;
        bbase[b] = bucketStartS[b] + blockHistS[(size_t)b * NBB + blockIdx.x];
    }
    __syncthreads();
    int base = blockIdx.x * EBS;
    int nrec = ESUB - base; if (nrec > EBS) nrec = EBS; if (nrec < 0) nrec = 0;

    for (int i = t; i < nrec; i += 512)
        atomicAdd(&cnt[met_sub[base + i] >> 9], 1);
    __syncthreads();
    int cval = (t < NBUCK_M) ? cnt[t] : 0;
    sc[t] = cval;
    __syncthreads();
    for (int off = 1; off < 512; off <<= 1) {
        int add = (t >= off) ? sc[t - off] : 0;
        __syncthreads();
        sc[t] += add;
        __syncthreads();
    }
    if (t < NBUCK_M) loff[t] = sc[t] - cval;
    __syncthreads();
    for (int i = t; i < nrec; i += 512) {
        int e = base + i;
        int m = met_sub[e];
        int b = m >> 9;
        float val = sto_sub[e] * v[rxn_sub[e]] * DT_C;
        int pos = loff[b] + atomicAdd(&rnk[b], 1);
        uint2 rec;
        rec.x = (unsigned)m;
        rec.y = __float_as_uint(val);
        stage[pos] = rec;
    }
    __syncthreads();
    for (int j = t; j < nrec; j += 512) {
        uint2 rec = stage[j];
        int b = (int)(rec.x >> 9);
        recsS[bbase[b] + (j - loff[b])] = rec;
    }
}

// ---- 8. per-bucket accumulate total -> met_scale ---------------------------
__global__ __launch_bounds__(512) void k_baccum_tot(
    const uint2* __restrict__ recsS, const int* __restrict__ bucketStartS,
    const float* __restrict__ x, float* __restrict__ met_scale)
{
    __shared__ float acc[512];
    int b = blockIdx.x;
    int t = threadIdx.x;
    acc[t] = 0.f;
    __syncthreads();
    int s = bucketStartS[b], epos = bucketStartS[b + 1];
    for (int i = s + t; i < epos; i += 512) {
        uint2 rec = recsS[i];
        atomicAdd(&acc[rec.x & 511], __uint_as_float(rec.y));
    }
    __syncthreads();
    int m = (b << 9) + t;
    if (m < NMET) {
        float tot = acc[t];
        float ms = 1.0f;
        if (tot > 1e-12f) ms = fminf(x[(size_t)m * 8 + 3] / tot, 1.0f);
        met_scale[m] = ms;
    }
}

// ---- 9. per-reaction min over CSR records + v scale ------------------------
__global__ __launch_bounds__(256) void k_rscale(
    const int* __restrict__ cntG, const int* __restrict__ offG,
    const uint2* __restrict__ recsC, const float* __restrict__ met_scale,
    float* __restrict__ v)
{
    int r = blockIdx.x * 256 + threadIdx.x;
    if (r >= NRXN) return;
    int n = cntG[r];
    int base = offG[r];
    float ms = 1.0f;
    for (int i = 0; i < n; ++i)
        ms = fminf(ms, met_scale[recsC[base + i].x & MET_MASK]);
    v[r] *= ms;
}

// ---- 10. contrib bucket-scatter with LDS counting-sort staging -------------
__global__ __launch_bounds__(512) void k_bscatter(
    const int* __restrict__ met_all, const int* __restrict__ rxn_all,
    const float* __restrict__ sto_all, const float* __restrict__ v,
    const int* __restrict__ blockHistA, const int* __restrict__ bucketStartA,
    uint2* __restrict__ recsA)
{
    __shared__ int cnt[NBUCK_M];
    __shared__ int loff[NBUCK_M];
    __shared__ int rnk[NBUCK_M];
    __shared__ int bbase[NBUCK_M];
    __shared__ int sc[512];
    __shared__ uint2 stage[EBA];
    int t = threadIdx.x;
    for (int b = t; b < NBUCK_M; b += 512) {
        cnt[b] = 0; rnk[b] = 0;
        bbase[b] = bucketStartA[b] + blockHistA[(size_t)b * NBB + blockIdx.x];
    }
    __syncthreads();
    int base = blockIdx.x * EBA;
    int nrec = EALL - base; if (nrec > EBA) nrec = EBA; if (nrec < 0) nrec = 0;

    for (int i = t; i < nrec; i += 512)
        atomicAdd(&cnt[met_all[base + i] >> 9], 1);
    __syncthreads();
    int cval = (t < NBUCK_M) ? cnt[t] : 0;
    sc[t] = cval;
    __syncthreads();
    for (int off = 1; off < 512; off <<= 1) {
        int add = (t >= off) ? sc[t - off] : 0;
        __syncthreads();
        sc[t] += add;
        __syncthreads();
    }
    if (t < NBUCK_M) loff[t] = sc[t] - cval;
    __syncthreads();
    for (int i = t; i < nrec; i += 512) {
        int e = base + i;
        int m = met_all[e];
        int b = m >> 9;
        float val = sto_all[e] * v[rxn_all[e]];
        int pos = loff[b] + atomicAdd(&rnk[b], 1);
        uint2 rec;
        rec.x = (unsigned)m;
        rec.y = __float_as_uint(val);
        stage[pos] = rec;
    }
    __syncthreads();
    for (int j = t; j < nrec; j += 512) {
        uint2 rec = stage[j];
        int b = (int)(rec.x >> 9);
        recsA[bbase[b] + (j - loff[b])] = rec;
    }
}

// ---- 11. per-bucket accumulate + homeostasis epilogue ----------------------
__global__ __launch_bounds__(512) void k_baccum(
    const uint2* __restrict__ recsA, const int* __restrict__ bucketStartA,
    const float* __restrict__ x, float* __restrict__ out)
{
    __shared__ float acc[512];
    int b = blockIdx.x;
    int t = threadIdx.x;
    acc[t] = 0.f;
    __syncthreads();
    int s = bucketStartA[b], epos = bucketStartA[b + 1];
    for (int i = s + t; i < epos; i += 512) {
        uint2 rec = recsA[i];
        atomicAdd(&acc[rec.x & 511], __uint_as_float(rec.y));
    }
    __syncthreads();
    int m = (b << 9) + t;
    if (m < NMET) {
        float c = x[(size_t)m * 8 + 3];
        out[m] = acc[t] - HOMEO_C * (c - C_TARGET);
    }
}

extern "C" void kernel_launch(void* const* d_in, const int* in_sizes, int n_in,
                              void* d_out, int out_size, void* d_ws, size_t ws_size,
                              hipStream_t stream) {
    const float* x       = (const float*)d_in[0];
    const int*   met_sub = (const int*)  d_in[1];
    const int*   rxn_sub = (const int*)  d_in[2];
    const float* sto_sub = (const float*)d_in[3];
    const int*   met_all = (const int*)  d_in[4];
    const int*   rxn_all = (const int*)  d_in[5];
    const float* sto_all = (const float*)d_in[6];
    const float* sub_w1  = (const float*)d_in[7];
    const float* sub_b1  = (const float*)d_in[8];
    const float* sub_w2  = (const float*)d_in[9];
    const float* sub_b2  = (const float*)d_in[10];
    const float* rate_w1 = (const float*)d_in[11];
    const float* rate_b1 = (const float*)d_in[12];
    const float* rate_w2 = (const float*)d_in[13];
    const float* rate_b2 = (const float*)d_in[14];
    const float* log_k   = (const float*)d_in[15];

    char* ws = (char*)d_ws;
    uint2* recsR = (uint2*)ws;                                  // ESUB
    uint2* recsC = recsR + ESUB;                                // ESUB
    uint2* recsS = recsC + ESUB;                                // ESUB
    uint2* recsA = recsS + ESUB;                                // EALL
    float* v     = (float*)(recsA + EALL);                      // NRXN
    float* met_scale = v + NRXN;                                // NMET
    int* cntG = (int*)(met_scale + NMET);                       // NBUCK_R*512
    int* offG = cntG + (size_t)NBUCK_R * 512;                   // NBUCK_R*512
    int* blockHistA = offG + (size_t)NBUCK_R * 512;             // NBUCK_M*NBB
    int* blockHistS = blockHistA + (size_t)NBUCK_M * NBB;       // NBUCK_M*NBB
    int* blockHistR = blockHistS + (size_t)NBUCK_M * NBB;       // NBUCK_R*NBB
    int* btotalA = blockHistR + (size_t)NBUCK_R * NBB;          // NBUCK_M
    int* bucketStartA = btotalA + NBUCK_M;                      // NBUCK_M+1
    int* btotalS = bucketStartA + NBUCK_M + 1;                  // NBUCK_M
    int* bucketStartS = btotalS + NBUCK_M;                      // NBUCK_M+1
    int* btotalR = bucketStartS + NBUCK_M + 1;                  // NBUCK_R
    int* bucketStartR = btotalR + NBUCK_R;                      // NBUCK_R+1
    float* out = (float*)d_out;

    dim3 blk256(256);
    dim3 blk512(512);
    k_count_all<<<dim3(NBB), blk512, 0, stream>>>(
        met_all, met_sub, rxn_sub, blockHistA, blockHistS, blockHistR);
    k_scan_all<<<dim3(2 * NBUCK_M + NBUCK_R), blk256, 0, stream>>>(
        blockHistA, blockHistS, blockHistR, btotalA, btotalS, btotalR);
    k_bstart3<<<dim3(3), dim3(1024), 0, stream>>>(
        btotalA, bucketStartA, btotalS, bucketStartS, btotalR, bucketStartR);
    k_rxn_scatter<<<dim3(NBB), blk512, 0, stream>>>(
        rxn_sub, met_sub, sto_sub, blockHistR, bucketStartR, recsR);
    k_csr_bucket<<<dim3(NBUCK_R), blk256, 0, stream>>>(
        recsR, bucketStartR, cntG, offG, recsC);
    k_bucket2<<<dim3(NBUCK_R), blk512, 0, stream>>>(
        recsC, bucketStartR, cntG, offG, x,
        sub_w1, sub_b1, sub_w2, sub_b2,
        rate_w1, rate_b1, rate_w2, rate_b2, log_k, v);
    k_cons_scatter<<<dim3(NBB), blk512, 0, stream>>>(
        met_sub, rxn_sub, sto_sub, v, blockHistS, bucketStartS, recsS);
    k_baccum_tot<<<dim3(NBUCK_M), blk512, 0, stream>>>(
        recsS, bucketStartS, x, met_scale);
    k_rscale<<<dim3((NRXN + 255) / 256), blk256, 0, stream>>>(
        cntG, offG, recsC, met_scale, v);
    k_bscatter<<<dim3(NBB), blk512, 0, stream>>>(
        met_all, rxn_all, sto_all, v, blockHistA, bucketStartA, recsA);
    k_baccum<<<dim3(NBUCK_M), blk512, 0, stream>>>(recsA, bucketStartA, x, out);
}